// Round 6
// baseline (5619.499 us; speedup 1.0000x reference)
//
#include <hip/hip_runtime.h>

typedef __attribute__((ext_vector_type(8))) short bf16x8_t;
typedef __attribute__((ext_vector_type(4))) float f32x4_t;

__device__ __forceinline__ ushort f2bf(float x) {
  union { float f; unsigned u; } a; a.f = x;
  unsigned r = a.u + 0x7fffu + ((a.u >> 16) & 1u);
  return (ushort)(r >> 16);
}
__device__ __forceinline__ float bf2f(ushort s) {
  union { unsigned u; float f; } a; a.u = ((unsigned)s) << 16;
  return a.f;
}
__device__ __forceinline__ void gload_lds16(const void* g, void* l) {
  __builtin_amdgcn_global_load_lds(
      (const __attribute__((address_space(1))) unsigned int*)g,
      (__attribute__((address_space(3))) unsigned int*)l, 16, 0, 0);
}

// ---------------- weight conversion ----------------
__global__ void cvt_kernel(const float* __restrict__ s, ushort* __restrict__ d, int n) {
  int i = blockIdx.x * 256 + threadIdx.x;
  if (i < n) d[i] = f2bf(s[i]);
}

__global__ void cvt4_kernel(const float* __restrict__ s, ushort* __restrict__ d, long n4) {
  long i = (long)blockIdx.x * 256 + threadIdx.x;
  if (i < n4) {
    float4 v = ((const float4*)s)[i];
    ushort4 o;
    o.x = f2bf(v.x); o.y = f2bf(v.y); o.z = f2bf(v.z); o.w = f2bf(v.w);
    ((ushort4*)d)[i] = o;
  }
}

// Wcat[l][r][c], r: 0-63 A_w, 64-127 B_w, 128-383 gate_w, 384-639 D_w
__global__ void build_wcat(const float* __restrict__ Aw, const float* __restrict__ Bw,
                           const float* __restrict__ gw, const float* __restrict__ Dw,
                           ushort* __restrict__ out) {
  int i = blockIdx.x * 256 + threadIdx.x;
  if (i >= 6 * 640 * 256) return;
  int l = i / (640 * 256), r = (i / 256) % 640, c = i % 256;
  float v;
  if (r < 64)        v = Aw[((l * 64 + r) * 256) + c];
  else if (r < 128)  v = Bw[((l * 64 + (r - 64)) * 256) + c];
  else if (r < 384)  v = gw[((l * 256 + (r - 128)) * 256) + c];
  else               v = Dw[((l * 256 + (r - 384)) * 256) + c];
  out[i] = f2bf(v);
}

// ========== G1: barrier-free GEMM. A 128xK resident in LDS (staged once);
// W fragments loaded per-wave global->register (L2-resident weights).
// MODE 1: bf16 out, col<64 tanh | <128 id | <384 sigmoid(v+b1[col-128]) | else v+b2[col-384]
// MODE 2: bf16 out = gelu_exact(v + b1[col])
template <int K, int NP, int MODE>
__global__ __launch_bounds__(256, 2)
void gemm_breg(const ushort* __restrict__ A, const ushort* __restrict__ W,
               const float* __restrict__ b1, const float* __restrict__ b2,
               ushort* __restrict__ outp) {
  constexpr int KS = K / 32;
  constexpr int N = NP * 128;
  constexpr int RB = 2 * K;       // row bytes
  constexpr int S = K / 8;        // 16B slots per row
  __shared__ __align__(16) char AsB[128 * RB];

  const int t = threadIdx.x, lane = t & 63, wid = t >> 6;
  const long m0 = (long)blockIdx.x * 128;
  const int wr = (wid >> 1) * 64, wc = (wid & 1) * 64;
  const char* Ab = (const char*)A;
  const char* Wb = (const char*)W;

  // stage resident A (swizzled source, linear LDS dest)
  constexpr int NJ = (128 * S / 64) / 4;
#pragma unroll
  for (int j = 0; j < NJ; ++j) {
    const int cc = j * 4 + wid;
    const int g = cc * 64 + lane;
    const int r = g / S, p = g % S;
    gload_lds16(Ab + (m0 + r) * RB + ((p ^ (r & 7)) << 4), AsB + cc * 1024);
  }

  const int krow = lane & 15, kslot = lane >> 4;
  const char* wbase[4];
  int abase[4], akey[4];
#pragma unroll
  for (int i = 0; i < 4; ++i) {
    wbase[i] = Wb + (long)(wc + i * 16 + krow) * RB + kslot * 16;
    const int ar = wr + i * 16 + krow;
    abase[i] = ar * RB;
    akey[i] = ar & 7;
  }

  const f32x4_t zero = {0.f, 0.f, 0.f, 0.f};
  f32x4_t acc[4][4];
  __syncthreads();   // A staged (drains vmcnt); only barrier in the kernel

  const int rbase = (lane >> 4) * 4, cbase = lane & 15;

  bf16x8_t bv[4];
#pragma unroll
  for (int i = 0; i < 4; ++i) bv[i] = *(const bf16x8_t*)(wbase[i]);

  for (int np = 0; np < NP; ++np) {
#pragma unroll
    for (int mi = 0; mi < 4; ++mi)
#pragma unroll
      for (int ni = 0; ni < 4; ++ni) acc[mi][ni] = zero;
    const long wno = (long)np * 128 * RB;

#pragma unroll
    for (int ks = 0; ks < KS; ++ks) {
      bf16x8_t bw[4];
      if (ks + 1 < KS) {
#pragma unroll
        for (int i = 0; i < 4; ++i) bw[i] = *(const bf16x8_t*)(wbase[i] + wno + (ks + 1) * 64);
      } else if (np + 1 < NP) {
#pragma unroll
        for (int i = 0; i < 4; ++i) bw[i] = *(const bf16x8_t*)(wbase[i] + wno + 128 * RB);
      } else {
#pragma unroll
        for (int i = 0; i < 4; ++i) bw[i] = bv[i];
      }
      bf16x8_t af[4];
      const int L = ks * 4 + kslot;
#pragma unroll
      for (int i = 0; i < 4; ++i)
        af[i] = *(const bf16x8_t*)(AsB + abase[i] + ((L ^ akey[i]) << 4));
#pragma unroll
      for (int mi = 0; mi < 4; ++mi)
#pragma unroll
        for (int ni = 0; ni < 4; ++ni)
          acc[mi][ni] = __builtin_amdgcn_mfma_f32_16x16x32_bf16(af[mi], bv[ni], acc[mi][ni], 0, 0, 0);
#pragma unroll
      for (int i = 0; i < 4; ++i) bv[i] = bw[i];
    }

#pragma unroll
    for (int mi = 0; mi < 4; ++mi) {
#pragma unroll
      for (int ni = 0; ni < 4; ++ni) {
        const int col = np * 128 + wc + ni * 16 + cbase;
#pragma unroll
        for (int j = 0; j < 4; ++j) {
          const long row = m0 + wr + mi * 16 + rbase + j;
          float v = acc[mi][ni][j];
          float o;
          if constexpr (MODE == 1) {
            if (col < 64)       o = tanhf(v);
            else if (col < 128) o = v;
            else if (col < 384) { float s = v + b1[col - 128]; o = 1.f / (1.f + expf(-s)); }
            else                o = v + b2[col - 384];
          } else {
            float s = v + b1[col];
            o = 0.5f * s * (1.f + erff(s * 0.70710678118654752f));
          }
          outp[row * N + col] = f2bf(o);
        }
      }
    }
  }
}

// ========== G2: barrier-free K=512 GEMM + fused residual + LayerNorm ==========
// A tile 64x512 resident; W (256x512) global->reg. MODE 0: v+b1; MODE 3: x+v+b1.
// Writes x (bf16, iff writex) and y = LN(xnew).
template <int MODE>
__global__ __launch_bounds__(256, 2)
void gemm_ln2(const ushort* __restrict__ A, const ushort* __restrict__ W,
              const float* __restrict__ b1, ushort* __restrict__ x,
              const float* __restrict__ lng, const float* __restrict__ lnb,
              ushort* __restrict__ y, int writex) {
  constexpr int K = 512, KS = 16, RB = 1024;
  __shared__ __align__(16) char AsB[64 * RB];   // 64 KB
  __shared__ float lsum2[64][2], lsq2[64][2];

  const int t = threadIdx.x, lane = t & 63, wid = t >> 6;
  const long m0 = (long)blockIdx.x * 64;
  const int wr = (wid >> 1) * 32, wc = (wid & 1) * 128;
  const char* Ab = (const char*)A;
  const char* Wb = (const char*)W;

  // stage A: chunk cc = one full row (1 KB)
#pragma unroll
  for (int j = 0; j < 16; ++j) {
    const int cc = j * 4 + wid;
    gload_lds16(Ab + (m0 + cc) * RB + ((lane ^ (cc & 7)) << 4), AsB + cc * 1024);
  }

  const int krow = lane & 15, kslot = lane >> 4;
  const char* wbase[8];
  int abase[2], akey[2];
#pragma unroll
  for (int i = 0; i < 8; ++i)
    wbase[i] = Wb + (long)(wc + i * 16 + krow) * RB + kslot * 16;
#pragma unroll
  for (int i = 0; i < 2; ++i) {
    const int ar = wr + i * 16 + krow;
    abase[i] = ar * RB;
    akey[i] = ar & 7;
  }

  const f32x4_t zero = {0.f, 0.f, 0.f, 0.f};
  f32x4_t acc[2][8];
#pragma unroll
  for (int i = 0; i < 2; ++i)
#pragma unroll
    for (int j = 0; j < 8; ++j) acc[i][j] = zero;

  __syncthreads();

  bf16x8_t bv[8];
#pragma unroll
  for (int i = 0; i < 8; ++i) bv[i] = *(const bf16x8_t*)(wbase[i]);

#pragma unroll
  for (int ks = 0; ks < KS; ++ks) {
    bf16x8_t bw[8];
    if (ks + 1 < KS) {
#pragma unroll
      for (int i = 0; i < 8; ++i) bw[i] = *(const bf16x8_t*)(wbase[i] + (ks + 1) * 64);
    } else {
#pragma unroll
      for (int i = 0; i < 8; ++i) bw[i] = bv[i];
    }
    bf16x8_t af[2];
    const int L = ks * 4 + kslot;
#pragma unroll
    for (int i = 0; i < 2; ++i)
      af[i] = *(const bf16x8_t*)(AsB + abase[i] + ((L ^ akey[i]) << 4));
#pragma unroll
    for (int mi = 0; mi < 2; ++mi)
#pragma unroll
      for (int ni = 0; ni < 8; ++ni)
        acc[mi][ni] = __builtin_amdgcn_mfma_f32_16x16x32_bf16(af[mi], bv[ni], acc[mi][ni], 0, 0, 0);
#pragma unroll
    for (int i = 0; i < 8; ++i) bv[i] = bw[i];
  }

  const int rbase = (lane >> 4) * 4, cbase = lane & 15;
  // residual
#pragma unroll
  for (int mi = 0; mi < 2; ++mi) {
#pragma unroll
    for (int ni = 0; ni < 8; ++ni) {
      const int col = wc + ni * 16 + cbase;
#pragma unroll
      for (int j = 0; j < 4; ++j) {
        const long row = m0 + wr + mi * 16 + rbase + j;
        float v = acc[mi][ni][j] + b1[col];
        if constexpr (MODE == 3) v += bf2f(x[row * 256 + col]);
        acc[mi][ni][j] = v;
      }
    }
  }
  // row partial stats (16-lane group = 16 cbase cols x 8 ni)
#pragma unroll
  for (int mi = 0; mi < 2; ++mi) {
#pragma unroll
    for (int j = 0; j < 4; ++j) {
      float ps = 0.f, pq = 0.f;
#pragma unroll
      for (int ni = 0; ni < 8; ++ni) { float v = acc[mi][ni][j]; ps += v; pq += v * v; }
#pragma unroll
      for (int off = 1; off < 16; off <<= 1) {
        ps += __shfl_xor(ps, off, 64);
        pq += __shfl_xor(pq, off, 64);
      }
      if ((lane & 15) == 0) {
        int r = wr + mi * 16 + (lane >> 4) * 4 + j;
        lsum2[r][wid & 1] = ps;
        lsq2[r][wid & 1] = pq;
      }
    }
  }
  __syncthreads();
#pragma unroll
  for (int mi = 0; mi < 2; ++mi) {
#pragma unroll
    for (int j = 0; j < 4; ++j) {
      const int r = wr + mi * 16 + rbase + j;
      const float s = lsum2[r][0] + lsum2[r][1];
      const float q = lsq2[r][0] + lsq2[r][1];
      const float mean = s * (1.f / 256.f);
      const float rstd = rsqrtf(q * (1.f / 256.f) - mean * mean + 1e-5f);
      const long row = m0 + r;
#pragma unroll
      for (int ni = 0; ni < 8; ++ni) {
        const int col = wc + ni * 16 + cbase;
        const float v = acc[mi][ni][j];
        if (writex) x[row * 256 + col] = f2bf(v);
        y[row * 256 + col] = f2bf((v - mean) * rstd * lng[col] + lnb[col]);
      }
    }
  }
}

// ========== G3: C-mix + gated combine + LayerNorm, barrier-free K=64 ==========
// ys = hs[M,64] @ Cw[256,64]^T; xnew = x + ys*g + dt*(1-g); y = LN(xnew).
__global__ __launch_bounds__(256, 2)
void gemm_cmix_ln(const ushort* __restrict__ A, const ushort* __restrict__ W,
                  const ushort* __restrict__ zgd, ushort* __restrict__ x,
                  const float* __restrict__ lng, const float* __restrict__ lnb,
                  ushort* __restrict__ y) {
  constexpr int RB = 128;   // 64 * 2
  __shared__ __align__(16) char AsB[128 * RB];  // 16 KB
  __shared__ float lsum2[128][2], lsq2[128][2];

  const int t = threadIdx.x, lane = t & 63, wid = t >> 6;
  const long m0 = (long)blockIdx.x * 128;
  const int wr = (wid >> 1) * 64, wc = (wid & 1) * 128;
  const char* Ab = (const char*)A;
  const char* Wb = (const char*)W;

  // stage A (hs): 16 chunks; r = cc*8 + lane/8, p = lane&7
#pragma unroll
  for (int j = 0; j < 4; ++j) {
    const int cc = j * 4 + wid;
    const int r = cc * 8 + (lane >> 3), p = lane & 7;
    gload_lds16(Ab + (m0 + r) * RB + ((p ^ (r & 7)) << 4), AsB + cc * 1024);
  }

  const int krow = lane & 15, kslot = lane >> 4;
  const char* wbase[8];
  int abase[4], akey[4];
#pragma unroll
  for (int i = 0; i < 8; ++i)
    wbase[i] = Wb + (long)(wc + i * 16 + krow) * RB + kslot * 16;
#pragma unroll
  for (int i = 0; i < 4; ++i) {
    const int ar = wr + i * 16 + krow;
    abase[i] = ar * RB;
    akey[i] = ar & 7;
  }

  const f32x4_t zero = {0.f, 0.f, 0.f, 0.f};
  f32x4_t acc[4][8];
#pragma unroll
  for (int i = 0; i < 4; ++i)
#pragma unroll
    for (int j = 0; j < 8; ++j) acc[i][j] = zero;

  __syncthreads();

#pragma unroll
  for (int ks = 0; ks < 2; ++ks) {
    bf16x8_t bv[8], af[4];
    const int L = ks * 4 + kslot;
#pragma unroll
    for (int i = 0; i < 8; ++i) bv[i] = *(const bf16x8_t*)(wbase[i] + ks * 64);
#pragma unroll
    for (int i = 0; i < 4; ++i)
      af[i] = *(const bf16x8_t*)(AsB + abase[i] + ((L ^ akey[i]) << 4));
#pragma unroll
    for (int mi = 0; mi < 4; ++mi)
#pragma unroll
      for (int ni = 0; ni < 8; ++ni)
        acc[mi][ni] = __builtin_amdgcn_mfma_f32_16x16x32_bf16(af[mi], bv[ni], acc[mi][ni], 0, 0, 0);
  }

  const int rbase = (lane >> 4) * 4, cbase = lane & 15;
  // combine: xnew = x + ys*g + dt*(1-g)
#pragma unroll
  for (int mi = 0; mi < 4; ++mi) {
#pragma unroll
    for (int ni = 0; ni < 8; ++ni) {
      const int col = wc + ni * 16 + cbase;
#pragma unroll
      for (int j = 0; j < 4; ++j) {
        const long row = m0 + wr + mi * 16 + rbase + j;
        const float v = acc[mi][ni][j];
        const float gv = bf2f(zgd[row * 640 + 128 + col]);
        const float dv = bf2f(zgd[row * 640 + 384 + col]);
        acc[mi][ni][j] = bf2f(x[row * 256 + col]) + v * gv + dv * (1.f - gv);
      }
    }
  }
#pragma unroll
  for (int mi = 0; mi < 4; ++mi) {
#pragma unroll
    for (int j = 0; j < 4; ++j) {
      float ps = 0.f, pq = 0.f;
#pragma unroll
      for (int ni = 0; ni < 8; ++ni) { float v = acc[mi][ni][j]; ps += v; pq += v * v; }
#pragma unroll
      for (int off = 1; off < 16; off <<= 1) {
        ps += __shfl_xor(ps, off, 64);
        pq += __shfl_xor(pq, off, 64);
      }
      if ((lane & 15) == 0) {
        int r = wr + mi * 16 + (lane >> 4) * 4 + j;
        lsum2[r][wid & 1] = ps;
        lsq2[r][wid & 1] = pq;
      }
    }
  }
  __syncthreads();
#pragma unroll
  for (int mi = 0; mi < 4; ++mi) {
#pragma unroll
    for (int j = 0; j < 4; ++j) {
      const int r = wr + mi * 16 + rbase + j;
      const float s = lsum2[r][0] + lsum2[r][1];
      const float q = lsq2[r][0] + lsq2[r][1];
      const float mean = s * (1.f / 256.f);
      const float rstd = rsqrtf(q * (1.f / 256.f) - mean * mean + 1e-5f);
      const long row = m0 + r;
#pragma unroll
      for (int ni = 0; ni < 8; ++ni) {
        const int col = wc + ni * 16 + cbase;
        const float v = acc[mi][ni][j];
        x[row * 256 + col] = f2bf(v);
        y[row * 256 + col] = f2bf((v - mean) * rstd * lng[col] + lnb[col]);
      }
    }
  }
}

// ---------------- scan ----------------
__global__ __launch_bounds__(256)
void scan_kernel(const ushort* __restrict__ z, ushort* __restrict__ hs) {
  const long tid = (long)blockIdx.x * 256 + threadIdx.x;
  const long b = tid >> 6;
  const int d = tid & 63;
  const ushort* zb = z + b * (16 * 640);
  ushort* hb = hs + b * (16 * 64);
  float h = 0.f;
#pragma unroll
  for (int s = 0; s < 16; ++s) {
    float a  = bf2f(zb[s * 640 + d]);
    float bt = bf2f(zb[s * 640 + 64 + d]);
    h = fmaf(a, h, bt);
    hb[s * 64 + d] = f2bf(h);
  }
}

// ---------------- head ----------------
__global__ __launch_bounds__(256)
void head_kernel(const ushort* __restrict__ yin, const float* __restrict__ attw,
                 const float* __restrict__ ow, const float* __restrict__ ob,
                 const float* __restrict__ cw, const float* __restrict__ cb,
                 float* __restrict__ out) {
  __shared__ float xf[16][256];
  __shared__ float lg[16], aw[16];
  __shared__ float vs[256], o1[128], lgc[40], lse[1];
  const int t = threadIdx.x, lane = t & 63, wid = t >> 6;
  const ushort* yb = yin + (long)blockIdx.x * 16 * 256;

  for (int r = wid; r < 16; r += 4) {
    ushort4 u = *(const ushort4*)(yb + r * 256 + lane * 4);
    int c = lane * 4;
    xf[r][c + 0] = bf2f(u.x);
    xf[r][c + 1] = bf2f(u.y);
    xf[r][c + 2] = bf2f(u.z);
    xf[r][c + 3] = bf2f(u.w);
  }
  __syncthreads();

  for (int r = wid; r < 16; r += 4) {
    const float* wv = attw + (r == 0 ? 0 : 256);
    int c = lane * 4;
    float s = xf[r][c] * wv[c] + xf[r][c + 1] * wv[c + 1] +
              xf[r][c + 2] * wv[c + 2] + xf[r][c + 3] * wv[c + 3];
#pragma unroll
    for (int off = 32; off > 0; off >>= 1) s += __shfl_xor(s, off, 64);
    if (lane == 0) lg[r] = s;
  }
  __syncthreads();

  if (t == 0) {
    float mx = -1e30f;
    for (int s2 = 1; s2 < 16; ++s2) mx = fmaxf(mx, lg[s2]);
    float den = 0.f;
    for (int s2 = 1; s2 < 16; ++s2) { float e = expf(lg[s2] - mx); aw[s2] = e; den += e; }
    float inv = 1.f / den;
    for (int s2 = 1; s2 < 16; ++s2) aw[s2] *= inv;
  }
  __syncthreads();

  float vh = xf[0][t];
  for (int s2 = 1; s2 < 16; ++s2) vh += aw[s2] * xf[s2][t];
  vs[t] = vh;
  __syncthreads();

  if (t < 128) {
    float s = ob[t];
    const float* w = ow + t * 256;
    for (int h2 = 0; h2 < 256; ++h2) s += w[h2] * vs[h2];
    o1[t] = fmaxf(s, 0.f);
  }
  __syncthreads();

  if (t < 40) {
    float s = cb[t];
    const float* w = cw + t * 128;
    for (int j = 0; j < 128; ++j) s += w[j] * o1[j];
    lgc[t] = s;
  }
  __syncthreads();

  if (t == 0) {
    float mx = -1e30f;
    for (int c2 = 0; c2 < 40; ++c2) mx = fmaxf(mx, lgc[c2]);
    float den = 0.f;
    for (int c2 = 0; c2 < 40; ++c2) den += expf(lgc[c2] - mx);
    lse[0] = mx + logf(den);
  }
  __syncthreads();
  if (t < 40) out[(long)blockIdx.x * 40 + t] = lgc[t] - lse[0];
}

// ---------------- host ----------------
extern "C" void kernel_launch(void* const* d_in, const int* in_sizes, int n_in,
                              void* d_out, int out_size, void* d_ws, size_t ws_size,
                              hipStream_t stream) {
  const float* data   = (const float*)d_in[0];
  const float* in_w   = (const float*)d_in[1];
  const float* in_b   = (const float*)d_in[2];
  const float* norm_g = (const float*)d_in[3];
  const float* norm_b = (const float*)d_in[4];
  const float* A_w    = (const float*)d_in[5];
  const float* B_w    = (const float*)d_in[6];
  const float* C_w    = (const float*)d_in[7];
  const float* D_w    = (const float*)d_in[8];
  const float* D_b    = (const float*)d_in[9];
  const float* gate_w = (const float*)d_in[10];
  const float* gate_b = (const float*)d_in[11];
  const float* ffn_w1 = (const float*)d_in[12];
  const float* ffn_b1 = (const float*)d_in[13];
  const float* ffn_w2 = (const float*)d_in[14];
  const float* ffn_b2 = (const float*)d_in[15];
  const float* fln_g  = (const float*)d_in[16];
  const float* fln_b  = (const float*)d_in[17];
  const float* out_w  = (const float*)d_in[18];
  const float* out_b  = (const float*)d_in[19];
  const float* cls_w  = (const float*)d_in[20];
  const float* cls_b  = (const float*)d_in[21];
  const float* attn_w = (const float*)d_in[22];
  const float* attn_b = (const float*)d_in[23];
  (void)in_sizes; (void)n_in; (void)out_size; (void)ws_size; (void)attn_b;

  char* ws = (char*)d_ws;
  ushort* x    = (ushort*)(ws + 0);           // 131072*256*2  =  67108864
  ushort* y    = (ushort*)(ws + 67108864);    // 131072*256*2  =  67108864
  ushort* z    = (ushort*)(ws + 134217728);   // 131072*640*2  = 167772160 (reused: datab, ffn1 t)
  ushort* hs   = (ushort*)(ws + 301989888);   // 131072*64*2   =  16777216
  ushort* wcat = (ushort*)(ws + 318767104);   // 6*640*256*2   =   1966080
  ushort* inwb = (ushort*)(ws + 320733184);   // 256*512*2     =    262144
  ushort* w1b  = (ushort*)(ws + 320995328);   // 6*512*256*2   =   1572864
  ushort* w2b  = (ushort*)(ws + 322568192);   // 6*256*512*2   =   1572864
  ushort* cwb  = (ushort*)(ws + 324141056);   // 6*256*64*2    =    196608
  ushort* datab = z;                          // consumed by input proj before z written

  cvt_kernel<<<512, 256, 0, stream>>>(in_w, inwb, 131072);
  cvt_kernel<<<3072, 256, 0, stream>>>(ffn_w1, w1b, 786432);
  cvt_kernel<<<3072, 256, 0, stream>>>(ffn_w2, w2b, 786432);
  cvt_kernel<<<384, 256, 0, stream>>>(C_w, cwb, 98304);
  build_wcat<<<3840, 256, 0, stream>>>(A_w, B_w, gate_w, D_w, wcat);
  cvt4_kernel<<<65536, 256, 0, stream>>>(data, datab, 16777216);

  // input proj + fused LN(layer0): x(bf16), y
  gemm_ln2<0><<<2048, 256, 0, stream>>>(datab, inwb, in_b, x, norm_g, norm_b, y, 1);

  for (int l = 0; l < 6; ++l) {
    gemm_breg<256, 5, 1><<<1024, 256, 0, stream>>>(
        y, wcat + (size_t)l * 640 * 256, gate_b + l * 256, D_b + l * 256, z);
    scan_kernel<<<2048, 256, 0, stream>>>(z, hs);
    gemm_cmix_ln<<<1024, 256, 0, stream>>>(
        hs, cwb + (size_t)l * 256 * 64, z, x, norm_g + l * 256, norm_b + l * 256, y);
    gemm_breg<256, 4, 2><<<1024, 256, 0, stream>>>(
        y, w1b + (size_t)l * 512 * 256, ffn_b1 + l * 512, nullptr, z);
    const float* lg2 = (l < 5) ? (norm_g + (l + 1) * 256) : fln_g;
    const float* lb2 = (l < 5) ? (norm_b + (l + 1) * 256) : fln_b;
    gemm_ln2<3><<<2048, 256, 0, stream>>>(
        z, w2b + (size_t)l * 256 * 512, ffn_b2 + l * 256, x, lg2, lb2, y, (l < 5) ? 1 : 0);
  }

  head_kernel<<<8192, 256, 0, stream>>>(y, attn_w, out_w, out_b, cls_w, cls_b, (float*)d_out);
}

// Round 7
// 3811.652 us; speedup vs baseline: 1.4743x; 1.4743x over previous
//
#include <hip/hip_runtime.h>

typedef __attribute__((ext_vector_type(8))) short bf16x8_t;
typedef __attribute__((ext_vector_type(4))) float f32x4_t;

__device__ __forceinline__ ushort f2bf(float x) {
  union { float f; unsigned u; } a; a.f = x;
  unsigned r = a.u + 0x7fffu + ((a.u >> 16) & 1u);
  return (ushort)(r >> 16);
}
__device__ __forceinline__ float bf2f(ushort s) {
  union { unsigned u; float f; } a; a.u = ((unsigned)s) << 16;
  return a.f;
}
__device__ __forceinline__ void gload_lds16(const void* g, void* l) {
  __builtin_amdgcn_global_load_lds(
      (const __attribute__((address_space(1))) unsigned int*)g,
      (__attribute__((address_space(3))) unsigned int*)l, 16, 0, 0);
}
__device__ __forceinline__ int swzkey(int r) { return ((r >> 2) ^ r) & 3; }

// ---------------- weight conversion ----------------
__global__ void cvt_kernel(const float* __restrict__ s, ushort* __restrict__ d, int n) {
  int i = blockIdx.x * 256 + threadIdx.x;
  if (i < n) d[i] = f2bf(s[i]);
}

__global__ void cvt4_kernel(const float* __restrict__ s, ushort* __restrict__ d, long n4) {
  long i = (long)blockIdx.x * 256 + threadIdx.x;
  if (i < n4) {
    float4 v = ((const float4*)s)[i];
    ushort4 o;
    o.x = f2bf(v.x); o.y = f2bf(v.y); o.z = f2bf(v.z); o.w = f2bf(v.w);
    ((ushort4*)d)[i] = o;
  }
}

// Wcat[l][r][c], r: 0-63 A_w, 64-127 B_w, 128-383 gate_w, 384-639 D_w
__global__ void build_wcat(const float* __restrict__ Aw, const float* __restrict__ Bw,
                           const float* __restrict__ gw, const float* __restrict__ Dw,
                           ushort* __restrict__ out) {
  int i = blockIdx.x * 256 + threadIdx.x;
  if (i >= 6 * 640 * 256) return;
  int l = i / (640 * 256), r = (i / 256) % 640, c = i % 256;
  float v;
  if (r < 64)        v = Aw[((l * 64 + r) * 256) + c];
  else if (r < 128)  v = Bw[((l * 64 + (r - 64)) * 256) + c];
  else if (r < 384)  v = gw[((l * 256 + (r - 128)) * 256) + c];
  else               v = Dw[((l * 256 + (r - 384)) * 256) + c];
  out[i] = f2bf(v);
}

// ========== G1: barrier-free GEMM. A 128xK resident in LDS (staged once);
// W fragments loaded per-wave global->register (L2-resident weights).
// MODE 1: bf16 out, col<64 tanh | <128 id | <384 sigmoid(v+b1[col-128]) | else v+b2[col-384]
// MODE 2: bf16 out = gelu_exact(v + b1[col])
template <int K, int NP, int MODE>
__global__ __launch_bounds__(256, 2)
void gemm_breg(const ushort* __restrict__ A, const ushort* __restrict__ W,
               const float* __restrict__ b1, const float* __restrict__ b2,
               ushort* __restrict__ outp) {
  constexpr int KS = K / 32;
  constexpr int N = NP * 128;
  constexpr int RB = 2 * K;       // row bytes
  constexpr int S = K / 8;        // 16B slots per row
  __shared__ __align__(16) char AsB[128 * RB];

  const int t = threadIdx.x, lane = t & 63, wid = t >> 6;
  const long m0 = (long)blockIdx.x * 128;
  const int wr = (wid >> 1) * 64, wc = (wid & 1) * 64;
  const char* Ab = (const char*)A;
  const char* Wb = (const char*)W;

  // stage resident A (swizzled source, linear LDS dest)
  constexpr int NJ = (128 * S / 64) / 4;
#pragma unroll
  for (int j = 0; j < NJ; ++j) {
    const int cc = j * 4 + wid;
    const int g = cc * 64 + lane;
    const int r = g / S, p = g % S;
    gload_lds16(Ab + (m0 + r) * RB + ((p ^ (r & 7)) << 4), AsB + cc * 1024);
  }

  const int krow = lane & 15, kslot = lane >> 4;
  const char* wbase[4];
  int abase[4], akey[4];
#pragma unroll
  for (int i = 0; i < 4; ++i) {
    wbase[i] = Wb + (long)(wc + i * 16 + krow) * RB + kslot * 16;
    const int ar = wr + i * 16 + krow;
    abase[i] = ar * RB;
    akey[i] = ar & 7;
  }

  const f32x4_t zero = {0.f, 0.f, 0.f, 0.f};
  f32x4_t acc[4][4];
  __syncthreads();   // A staged (drains vmcnt); only barrier in the kernel

  const int rbase = (lane >> 4) * 4, cbase = lane & 15;

  bf16x8_t bv[4];
#pragma unroll
  for (int i = 0; i < 4; ++i) bv[i] = *(const bf16x8_t*)(wbase[i]);

  for (int np = 0; np < NP; ++np) {
#pragma unroll
    for (int mi = 0; mi < 4; ++mi)
#pragma unroll
      for (int ni = 0; ni < 4; ++ni) acc[mi][ni] = zero;
    const long wno = (long)np * 128 * RB;

#pragma unroll
    for (int ks = 0; ks < KS; ++ks) {
      bf16x8_t bw[4];
      if (ks + 1 < KS) {
#pragma unroll
        for (int i = 0; i < 4; ++i) bw[i] = *(const bf16x8_t*)(wbase[i] + wno + (ks + 1) * 64);
      } else if (np + 1 < NP) {
#pragma unroll
        for (int i = 0; i < 4; ++i) bw[i] = *(const bf16x8_t*)(wbase[i] + wno + 128 * RB);
      } else {
#pragma unroll
        for (int i = 0; i < 4; ++i) bw[i] = bv[i];
      }
      bf16x8_t af[4];
      const int L = ks * 4 + kslot;
#pragma unroll
      for (int i = 0; i < 4; ++i)
        af[i] = *(const bf16x8_t*)(AsB + abase[i] + ((L ^ akey[i]) << 4));
#pragma unroll
      for (int mi = 0; mi < 4; ++mi)
#pragma unroll
        for (int ni = 0; ni < 4; ++ni)
          acc[mi][ni] = __builtin_amdgcn_mfma_f32_16x16x32_bf16(af[mi], bv[ni], acc[mi][ni], 0, 0, 0);
#pragma unroll
      for (int i = 0; i < 4; ++i) bv[i] = bw[i];
    }

#pragma unroll
    for (int mi = 0; mi < 4; ++mi) {
#pragma unroll
      for (int ni = 0; ni < 4; ++ni) {
        const int col = np * 128 + wc + ni * 16 + cbase;
#pragma unroll
        for (int j = 0; j < 4; ++j) {
          const long row = m0 + wr + mi * 16 + rbase + j;
          float v = acc[mi][ni][j];
          float o;
          if constexpr (MODE == 1) {
            if (col < 64)       o = tanhf(v);
            else if (col < 128) o = v;
            else if (col < 384) { float s = v + b1[col - 128]; o = 1.f / (1.f + expf(-s)); }
            else                o = v + b2[col - 384];
          } else {
            float s = v + b1[col];
            o = 0.5f * s * (1.f + erff(s * 0.70710678118654752f));
          }
          outp[row * N + col] = f2bf(o);
        }
      }
    }
  }
}

// ========== G2: C-mix GEMM (proven R4 shape): x += ys*g + dt*(1-g), x bf16 RMW ==========
__global__ __launch_bounds__(256)
void gemm_cmix(const ushort* __restrict__ A, const ushort* __restrict__ W,
               const ushort* __restrict__ zgd, ushort* __restrict__ x) {
  constexpr int K = 64;
  __shared__ __align__(16) ushort As[128 * 32];
  __shared__ __align__(16) ushort Ws[128 * 32];

  const int t = threadIdx.x, lane = t & 63, wid = t >> 6;
  const long m0 = (long)blockIdx.x * 128;
  const int n0 = blockIdx.y * 128;
  const int wr = (wid >> 1) * 64, wc = (wid & 1) * 64;
  const int c0 = wid * 2;
  const int r0 = c0 * 16 + (lane >> 2), r1 = r0 + 16;
  const int cb0 = (((lane & 3) ^ swzkey(r0)) << 4);
  const int cb1 = (((lane & 3) ^ swzkey(r1)) << 4);
  const char* Ab = (const char*)A;
  const char* Wb = (const char*)W;
  constexpr long K2 = (long)K * 2;

  const int krow = lane & 15, kslot = lane >> 4;
  int aoff[4], boff[4];
#pragma unroll
  for (int i = 0; i < 4; ++i) {
    int ar = wr + i * 16 + krow;
    aoff[i] = ar * 64 + ((kslot ^ swzkey(ar)) << 4);
    int br = wc + i * 16 + krow;
    boff[i] = br * 64 + ((kslot ^ swzkey(br)) << 4);
  }

  const f32x4_t zero = {0.f, 0.f, 0.f, 0.f};
  f32x4_t acc[4][4];
#pragma unroll
  for (int i = 0; i < 4; ++i)
#pragma unroll
    for (int j = 0; j < 4; ++j) acc[i][j] = zero;

  for (int k0 = 0; k0 < K; k0 += 32) {
    const long kb = (long)k0 * 2;
    gload_lds16(Ab + (m0 + r0) * K2 + kb + cb0, (char*)As + c0 * 1024);
    gload_lds16(Ab + (m0 + r1) * K2 + kb + cb1, (char*)As + c0 * 1024 + 1024);
    gload_lds16(Wb + (long)(n0 + r0) * K2 + kb + cb0, (char*)Ws + c0 * 1024);
    gload_lds16(Wb + (long)(n0 + r1) * K2 + kb + cb1, (char*)Ws + c0 * 1024 + 1024);
    __syncthreads();

    bf16x8_t af[4], bv[4];
#pragma unroll
    for (int i = 0; i < 4; ++i) af[i] = *(const bf16x8_t*)((const char*)As + aoff[i]);
#pragma unroll
    for (int i = 0; i < 4; ++i) bv[i] = *(const bf16x8_t*)((const char*)Ws + boff[i]);
#pragma unroll
    for (int mi = 0; mi < 4; ++mi)
#pragma unroll
      for (int ni = 0; ni < 4; ++ni)
        acc[mi][ni] = __builtin_amdgcn_mfma_f32_16x16x32_bf16(af[mi], bv[ni], acc[mi][ni], 0, 0, 0);
    __syncthreads();
  }

  const int rbase = (lane >> 4) * 4;
  const int cbase = lane & 15;
#pragma unroll
  for (int mi = 0; mi < 4; ++mi) {
#pragma unroll
    for (int ni = 0; ni < 4; ++ni) {
      const int col = n0 + wc + ni * 16 + cbase;
#pragma unroll
      for (int j = 0; j < 4; ++j) {
        const long row = m0 + wr + mi * 16 + rbase + j;
        float v = acc[mi][ni][j];
        float gv = bf2f(zgd[row * 640 + 128 + col]);
        float dv = bf2f(zgd[row * 640 + 384 + col]);
        float xo = bf2f(x[row * 256 + col]);
        x[row * 256 + col] = f2bf(xo + v * gv + dv * (1.f - gv));
      }
    }
  }
}

// ========== G3: N=256 full-row GEMM with fused residual + LayerNorm (x bf16) ==========
// MODE 0: xnew = v + b1[col]            MODE 3: xnew = x[row,col] + v + b1[col]
template <int K, int MODE>
__global__ __launch_bounds__(512)
void gemm_ln(const ushort* __restrict__ A, const ushort* __restrict__ W,
             const float* __restrict__ b1, ushort* __restrict__ x,
             const float* __restrict__ lng, const float* __restrict__ lnb,
             ushort* __restrict__ y, int writex) {
  constexpr int KS = K / 32;
  __shared__ __align__(16) char WsB[2 * 16384];
  __shared__ __align__(16) char AsB[2 * 8192];
  __shared__ float lsum4[128][4], lsq4[128][4];

  const int t = threadIdx.x, lane = t & 63, wid = t >> 6;
  const int wr = (wid >> 2) * 64, wc = (wid & 3) * 64;
  const int lr = lane >> 2, lc = lane & 3;
  const int ra = wid * 16 + lr;
  const int saA = (lc ^ swzkey(ra)) << 4;
  const int rw0 = wid * 32 + lr, rw1 = rw0 + 16;
  const int sw0 = (lc ^ swzkey(rw0)) << 4;
  const int sw1 = (lc ^ swzkey(rw1)) << 4;
  const char* Ab = (const char*)A;
  const char* Wb = (const char*)W;
  constexpr long K2 = (long)K * 2;
  const long m0 = (long)blockIdx.x * 128;

  gload_lds16(Wb + (long)rw0 * K2 + sw0, WsB + wid * 2048);
  gload_lds16(Wb + (long)rw1 * K2 + sw1, WsB + wid * 2048 + 1024);
  gload_lds16(Ab + (m0 + ra) * K2 + saA, AsB + wid * 1024);

  const int krow = lane & 15, kslot = lane >> 4;
  int aoff[4], boff[4];
#pragma unroll
  for (int i = 0; i < 4; ++i) {
    int ar = wr + i * 16 + krow;
    aoff[i] = ar * 64 + ((kslot ^ swzkey(ar)) << 4);
    int br = wc + i * 16 + krow;
    boff[i] = br * 64 + ((kslot ^ swzkey(br)) << 4);
  }

  const f32x4_t zero = {0.f, 0.f, 0.f, 0.f};
  f32x4_t acc[4][4];
#pragma unroll
  for (int i = 0; i < 4; ++i)
#pragma unroll
    for (int j = 0; j < 4; ++j) acc[i][j] = zero;

  for (int tau = 0; tau < KS; ++tau) {
    __syncthreads();
    if (tau + 1 < KS) {
      const long kb = (long)(tau + 1) * 64;
      gload_lds16(Ab + (m0 + ra) * K2 + kb + saA, AsB + ((tau + 1) & 1) * 8192 + wid * 1024);
      char* wd = WsB + ((tau + 1) & 1) * 16384 + wid * 2048;
      gload_lds16(Wb + (long)rw0 * K2 + kb + sw0, wd);
      gload_lds16(Wb + (long)rw1 * K2 + kb + sw1, wd + 1024);
    }
    const char* Ac = AsB + (tau & 1) * 8192;
    const char* Wc = WsB + (tau & 1) * 16384;
    bf16x8_t af[4], bv[4];
#pragma unroll
    for (int i = 0; i < 4; ++i) af[i] = *(const bf16x8_t*)(Ac + aoff[i]);
#pragma unroll
    for (int i = 0; i < 4; ++i) bv[i] = *(const bf16x8_t*)(Wc + boff[i]);
#pragma unroll
    for (int mi = 0; mi < 4; ++mi)
#pragma unroll
      for (int ni = 0; ni < 4; ++ni)
        acc[mi][ni] = __builtin_amdgcn_mfma_f32_16x16x32_bf16(af[mi], bv[ni], acc[mi][ni], 0, 0, 0);
  }

  const int rbase = (lane >> 4) * 4;
  const int cbase = lane & 15;
#pragma unroll
  for (int mi = 0; mi < 4; ++mi) {
#pragma unroll
    for (int ni = 0; ni < 4; ++ni) {
      const int col = wc + ni * 16 + cbase;
#pragma unroll
      for (int j = 0; j < 4; ++j) {
        const long row = m0 + wr + mi * 16 + rbase + j;
        float v = acc[mi][ni][j] + b1[col];
        if constexpr (MODE == 3) v += bf2f(x[row * 256 + col]);
        acc[mi][ni][j] = v;
      }
    }
  }
#pragma unroll
  for (int mi = 0; mi < 4; ++mi) {
#pragma unroll
    for (int j = 0; j < 4; ++j) {
      float ps = 0.f, pq = 0.f;
#pragma unroll
      for (int ni = 0; ni < 4; ++ni) { float v = acc[mi][ni][j]; ps += v; pq += v * v; }
#pragma unroll
      for (int off = 1; off < 16; off <<= 1) {
        ps += __shfl_xor(ps, off, 64);
        pq += __shfl_xor(pq, off, 64);
      }
      if ((lane & 15) == 0) {
        int r = wr + mi * 16 + (lane >> 4) * 4 + j;
        lsum4[r][wid & 3] = ps;
        lsq4[r][wid & 3] = pq;
      }
    }
  }
  __syncthreads();
#pragma unroll
  for (int mi = 0; mi < 4; ++mi) {
#pragma unroll
    for (int j = 0; j < 4; ++j) {
      const int r = wr + mi * 16 + rbase + j;
      const float s = lsum4[r][0] + lsum4[r][1] + lsum4[r][2] + lsum4[r][3];
      const float q = lsq4[r][0] + lsq4[r][1] + lsq4[r][2] + lsq4[r][3];
      const float mean = s * (1.f / 256.f);
      const float rstd = rsqrtf(q * (1.f / 256.f) - mean * mean + 1e-5f);
      const long row = m0 + r;
#pragma unroll
      for (int ni = 0; ni < 4; ++ni) {
        const int col = wc + ni * 16 + cbase;
        const float v = acc[mi][ni][j];
        if (writex) x[row * 256 + col] = f2bf(v);
        y[row * 256 + col] = f2bf((v - mean) * rstd * lng[col] + lnb[col]);
      }
    }
  }
}

// ---------------- LayerNorm: bf16 in -> bf16 out ----------------
__global__ __launch_bounds__(256)
void ln_kernel(const ushort* __restrict__ x, const float* __restrict__ g,
               const float* __restrict__ b, ushort* __restrict__ y) {
  const int lane = threadIdx.x & 63;
  const long row = (long)blockIdx.x * 4 + (threadIdx.x >> 6);
  const ushort4 u = *(const ushort4*)(x + row * 256 + lane * 4);
  float v0 = bf2f(u.x), v1 = bf2f(u.y), v2 = bf2f(u.z), v3 = bf2f(u.w);
  float s = v0 + v1 + v2 + v3;
  float q = v0 * v0 + v1 * v1 + v2 * v2 + v3 * v3;
#pragma unroll
  for (int off = 32; off > 0; off >>= 1) {
    s += __shfl_xor(s, off, 64);
    q += __shfl_xor(q, off, 64);
  }
  const float mean = s * (1.f / 256.f);
  const float rstd = rsqrtf(q * (1.f / 256.f) - mean * mean + 1e-5f);
  const int c = lane * 4;
  const float4 gv = *(const float4*)(g + c);
  const float4 bv = *(const float4*)(b + c);
  ushort4 o;
  o.x = f2bf((v0 - mean) * rstd * gv.x + bv.x);
  o.y = f2bf((v1 - mean) * rstd * gv.y + bv.y);
  o.z = f2bf((v2 - mean) * rstd * gv.z + bv.z);
  o.w = f2bf((v3 - mean) * rstd * gv.w + bv.w);
  *(ushort4*)(y + row * 256 + c) = o;
}

// ---------------- scan ----------------
__global__ __launch_bounds__(256)
void scan_kernel(const ushort* __restrict__ z, ushort* __restrict__ hs) {
  const long tid = (long)blockIdx.x * 256 + threadIdx.x;
  const long b = tid >> 6;
  const int d = tid & 63;
  const ushort* zb = z + b * (16 * 640);
  ushort* hb = hs + b * (16 * 64);
  float h = 0.f;
#pragma unroll
  for (int s = 0; s < 16; ++s) {
    float a  = bf2f(zb[s * 640 + d]);
    float bt = bf2f(zb[s * 640 + 64 + d]);
    h = fmaf(a, h, bt);
    hb[s * 64 + d] = f2bf(h);
  }
}

// ---------------- head ----------------
__global__ __launch_bounds__(256)
void head_kernel(const ushort* __restrict__ yin, const float* __restrict__ attw,
                 const float* __restrict__ ow, const float* __restrict__ ob,
                 const float* __restrict__ cw, const float* __restrict__ cb,
                 float* __restrict__ out) {
  __shared__ float xf[16][256];
  __shared__ float lg[16], aw[16];
  __shared__ float vs[256], o1[128], lgc[40], lse[1];
  const int t = threadIdx.x, lane = t & 63, wid = t >> 6;
  const ushort* yb = yin + (long)blockIdx.x * 16 * 256;

  for (int r = wid; r < 16; r += 4) {
    ushort4 u = *(const ushort4*)(yb + r * 256 + lane * 4);
    int c = lane * 4;
    xf[r][c + 0] = bf2f(u.x);
    xf[r][c + 1] = bf2f(u.y);
    xf[r][c + 2] = bf2f(u.z);
    xf[r][c + 3] = bf2f(u.w);
  }
  __syncthreads();

  for (int r = wid; r < 16; r += 4) {
    const float* wv = attw + (r == 0 ? 0 : 256);
    int c = lane * 4;
    float s = xf[r][c] * wv[c] + xf[r][c + 1] * wv[c + 1] +
              xf[r][c + 2] * wv[c + 2] + xf[r][c + 3] * wv[c + 3];
#pragma unroll
    for (int off = 32; off > 0; off >>= 1) s += __shfl_xor(s, off, 64);
    if (lane == 0) lg[r] = s;
  }
  __syncthreads();

  if (t == 0) {
    float mx = -1e30f;
    for (int s2 = 1; s2 < 16; ++s2) mx = fmaxf(mx, lg[s2]);
    float den = 0.f;
    for (int s2 = 1; s2 < 16; ++s2) { float e = expf(lg[s2] - mx); aw[s2] = e; den += e; }
    float inv = 1.f / den;
    for (int s2 = 1; s2 < 16; ++s2) aw[s2] *= inv;
  }
  __syncthreads();

  float vh = xf[0][t];
  for (int s2 = 1; s2 < 16; ++s2) vh += aw[s2] * xf[s2][t];
  vs[t] = vh;
  __syncthreads();

  if (t < 128) {
    float s = ob[t];
    const float* w = ow + t * 256;
    for (int h2 = 0; h2 < 256; ++h2) s += w[h2] * vs[h2];
    o1[t] = fmaxf(s, 0.f);
  }
  __syncthreads();

  if (t < 40) {
    float s = cb[t];
    const float* w = cw + t * 128;
    for (int j = 0; j < 128; ++j) s += w[j] * o1[j];
    lgc[t] = s;
  }
  __syncthreads();

  if (t == 0) {
    float mx = -1e30f;
    for (int c2 = 0; c2 < 40; ++c2) mx = fmaxf(mx, lgc[c2]);
    float den = 0.f;
    for (int c2 = 0; c2 < 40; ++c2) den += expf(lgc[c2] - mx);
    lse[0] = mx + logf(den);
  }
  __syncthreads();
  if (t < 40) out[(long)blockIdx.x * 40 + t] = lgc[t] - lse[0];
}

// ---------------- host ----------------
extern "C" void kernel_launch(void* const* d_in, const int* in_sizes, int n_in,
                              void* d_out, int out_size, void* d_ws, size_t ws_size,
                              hipStream_t stream) {
  const float* data   = (const float*)d_in[0];
  const float* in_w   = (const float*)d_in[1];
  const float* in_b   = (const float*)d_in[2];
  const float* norm_g = (const float*)d_in[3];
  const float* norm_b = (const float*)d_in[4];
  const float* A_w    = (const float*)d_in[5];
  const float* B_w    = (const float*)d_in[6];
  const float* C_w    = (const float*)d_in[7];
  const float* D_w    = (const float*)d_in[8];
  const float* D_b    = (const float*)d_in[9];
  const float* gate_w = (const float*)d_in[10];
  const float* gate_b = (const float*)d_in[11];
  const float* ffn_w1 = (const float*)d_in[12];
  const float* ffn_b1 = (const float*)d_in[13];
  const float* ffn_w2 = (const float*)d_in[14];
  const float* ffn_b2 = (const float*)d_in[15];
  const float* fln_g  = (const float*)d_in[16];
  const float* fln_b  = (const float*)d_in[17];
  const float* out_w  = (const float*)d_in[18];
  const float* out_b  = (const float*)d_in[19];
  const float* cls_w  = (const float*)d_in[20];
  const float* cls_b  = (const float*)d_in[21];
  const float* attn_w = (const float*)d_in[22];
  const float* attn_b = (const float*)d_in[23];
  (void)in_sizes; (void)n_in; (void)out_size; (void)ws_size; (void)attn_b;

  char* ws = (char*)d_ws;
  ushort* x    = (ushort*)(ws + 0);           // 131072*256*2  =  67108864
  ushort* y    = (ushort*)(ws + 67108864);    // 131072*256*2  =  67108864
  ushort* z    = (ushort*)(ws + 134217728);   // 131072*640*2  = 167772160 (reused: datab, ffn1 t)
  ushort* hs   = (ushort*)(ws + 301989888);   // 131072*64*2   =  16777216
  ushort* wcat = (ushort*)(ws + 318767104);   // 6*640*256*2   =   1966080
  ushort* inwb = (ushort*)(ws + 320733184);   // 256*512*2     =    262144
  ushort* w1b  = (ushort*)(ws + 320995328);   // 6*512*256*2   =   1572864
  ushort* w2b  = (ushort*)(ws + 322568192);   // 6*256*512*2   =   1572864
  ushort* cwb  = (ushort*)(ws + 324141056);   // 6*256*64*2    =    196608
  ushort* datab = z;                          // consumed by input proj before z written

  cvt_kernel<<<512, 256, 0, stream>>>(in_w, inwb, 131072);
  cvt_kernel<<<3072, 256, 0, stream>>>(ffn_w1, w1b, 786432);
  cvt_kernel<<<3072, 256, 0, stream>>>(ffn_w2, w2b, 786432);
  cvt_kernel<<<384, 256, 0, stream>>>(C_w, cwb, 98304);
  build_wcat<<<3840, 256, 0, stream>>>(A_w, B_w, gate_w, D_w, wcat);
  cvt4_kernel<<<65536, 256, 0, stream>>>(data, datab, 16777216);

  // input proj + fused LN(layer0): x(bf16), y
  gemm_ln<512, 0><<<dim3(1024), 512, 0, stream>>>(
      datab, inwb, in_b, x, norm_g, norm_b, y, 1);

  for (int l = 0; l < 6; ++l) {
    gemm_breg<256, 5, 1><<<1024, 256, 0, stream>>>(
        y, wcat + (size_t)l * 640 * 256, gate_b + l * 256, D_b + l * 256, z);
    scan_kernel<<<2048, 256, 0, stream>>>(z, hs);
    gemm_cmix<<<dim3(1024, 2), 256, 0, stream>>>(
        hs, cwb + (size_t)l * 256 * 64, z, x);
    ln_kernel<<<32768, 256, 0, stream>>>(x, norm_g + l * 256, norm_b + l * 256, y);
    gemm_breg<256, 4, 2><<<1024, 256, 0, stream>>>(
        y, w1b + (size_t)l * 512 * 256, ffn_b1 + l * 512, nullptr, z);
    const float* lg2 = (l < 5) ? (norm_g + (l + 1) * 256) : fln_g;
    const float* lb2 = (l < 5) ? (norm_b + (l + 1) * 256) : fln_b;
    gemm_ln<512, 3><<<dim3(1024), 512, 0, stream>>>(
        z, w2b + (size_t)l * 256 * 512, ffn_b2 + l * 256, x, lg2, lb2, y, (l < 5) ? 1 : 0);
  }

  head_kernel<<<8192, 256, 0, stream>>>(y, attn_w, out_w, out_b, cls_w, cls_b, (float*)d_out);
}

// Round 8
// 3354.328 us; speedup vs baseline: 1.6753x; 1.1363x over previous
//
#include <hip/hip_runtime.h>

typedef __attribute__((ext_vector_type(8))) short bf16x8_t;
typedef __attribute__((ext_vector_type(4))) float f32x4_t;

__device__ __forceinline__ ushort f2bf(float x) {
  union { float f; unsigned u; } a; a.f = x;
  unsigned r = a.u + 0x7fffu + ((a.u >> 16) & 1u);
  return (ushort)(r >> 16);
}
__device__ __forceinline__ float bf2f(ushort s) {
  union { unsigned u; float f; } a; a.u = ((unsigned)s) << 16;
  return a.f;
}
__device__ __forceinline__ void gload_lds16(const void* g, void* l) {
  __builtin_amdgcn_global_load_lds(
      (const __attribute__((address_space(1))) unsigned int*)g,
      (__attribute__((address_space(3))) unsigned int*)l, 16, 0, 0);
}
__device__ __forceinline__ int swzkey(int r) { return ((r >> 2) ^ r) & 3; }

// ---------------- weight conversion ----------------
__global__ void cvt_kernel(const float* __restrict__ s, ushort* __restrict__ d, int n) {
  int i = blockIdx.x * 256 + threadIdx.x;
  if (i < n) d[i] = f2bf(s[i]);
}

__global__ void cvt4_kernel(const float* __restrict__ s, ushort* __restrict__ d, long n4) {
  long i = (long)blockIdx.x * 256 + threadIdx.x;
  if (i < n4) {
    float4 v = ((const float4*)s)[i];
    ushort4 o;
    o.x = f2bf(v.x); o.y = f2bf(v.y); o.z = f2bf(v.z); o.w = f2bf(v.w);
    ((ushort4*)d)[i] = o;
  }
}

// Wcat[l][r][c], r: 0-63 A_w, 64-127 B_w, 128-383 gate_w, 384-639 D_w
__global__ void build_wcat(const float* __restrict__ Aw, const float* __restrict__ Bw,
                           const float* __restrict__ gw, const float* __restrict__ Dw,
                           ushort* __restrict__ out) {
  int i = blockIdx.x * 256 + threadIdx.x;
  if (i >= 6 * 640 * 256) return;
  int l = i / (640 * 256), r = (i / 256) % 640, c = i % 256;
  float v;
  if (r < 64)        v = Aw[((l * 64 + r) * 256) + c];
  else if (r < 128)  v = Bw[((l * 64 + (r - 64)) * 256) + c];
  else if (r < 384)  v = gw[((l * 256 + (r - 128)) * 256) + c];
  else               v = Dw[((l * 256 + (r - 384)) * 256) + c];
  out[i] = f2bf(v);
}

// repack row-major [N][256] bf16 -> k-sliced [p][ks][r][s][e], slot s holds logical
// slot s ^ ((r>>1)&3); slice (p,ks) is 8KB contiguous.
__global__ void repack_ks(const ushort* __restrict__ src, ushort* __restrict__ dst,
                          int N, int nmat) {
  const int perMat = N * 256;
  const long total = (long)nmat * perMat;
  const long i = (long)blockIdx.x * 256 + threadIdx.x;
  if (i >= total) return;
  const int m = (int)(i / perMat);
  const int idx = (int)(i % perMat);
  const int p = idx >> 15;              // panel (32768 elems each)
  const int idx2 = idx & 32767;
  const int ks = idx2 >> 12;            // 0..7
  const int r = (idx2 >> 5) & 127;
  const int s = (idx2 >> 3) & 3;
  const int e = idx2 & 7;
  const int k = ks * 32 + ((s ^ ((r >> 1) & 3)) << 3) + e;
  dst[(long)m * perMat + idx] = src[(long)m * perMat + (p * 128 + r) * 256 + k];
}

// ========== G1: A-stationary GEMM, k-sliced W (coalesced staging). K=256.
// A 128x256 resident in LDS; W slices (8KB) double-buffered, streamed sequentially.
// MODE 1: bf16 out, col<64 tanh | <128 id | <384 sigmoid(v+b1[col-128]) | else v+b2[col-384]
// MODE 2: bf16 out = gelu_exact(v + b1[col])
template <int NP, int MODE>
__global__ __launch_bounds__(256, 2)
void gemm_ws(const ushort* __restrict__ A, const ushort* __restrict__ Wks,
             const float* __restrict__ b1, const float* __restrict__ b2,
             ushort* __restrict__ outp) {
  constexpr int KS = 8;                 // 256/32
  constexpr int N = NP * 128;
  constexpr int T = NP * KS;
  __shared__ __align__(16) char AsB[128 * 512];   // 64KB resident A
  __shared__ __align__(16) char WsB[2 * 8192];    // W slice double buffer

  const int t = threadIdx.x, lane = t & 63, wid = t >> 6;
  const long m0 = (long)blockIdx.x * 128;
  const int wr = (wid >> 1) * 64, wc = (wid & 1) * 64;
  const char* Ab = (const char*)A;
  const char* Wb = (const char*)Wks;

  // ---- stage resident A: 16 x 1KB-contiguous wave loads ----
  {
    const int arow = lane >> 5;          // 0/1
    const int aps  = lane & 31;          // physical 16B slot
#pragma unroll
    for (int j = 0; j < 16; ++j) {
      const int r = j * 8 + wid * 2 + arow;
      gload_lds16(Ab + (m0 + r) * 512 + (long)((aps ^ (r & 7)) << 4),
                  AsB + (j * 8 + wid * 2) * 512);
    }
  }
  // ---- stage W slice 0 ----
  {
    const int co = wid * 2;
    gload_lds16(Wb + co * 1024 + lane * 16, WsB + co * 1024);
    gload_lds16(Wb + (co + 1) * 1024 + lane * 16, WsB + (co + 1) * 1024);
  }

  const int krow = lane & 15, kslot = lane >> 4;
  int abase[4], akey[4], boff[4];
#pragma unroll
  for (int i = 0; i < 4; ++i) {
    const int ar = wr + i * 16 + krow;
    abase[i] = ar * 512;
    akey[i] = ar & 7;
    const int br = wc + i * 16 + krow;
    boff[i] = br * 64 + ((kslot ^ ((br >> 1) & 3)) << 4);
  }

  const f32x4_t zero = {0.f, 0.f, 0.f, 0.f};
  f32x4_t acc[4][4];
#pragma unroll
  for (int i = 0; i < 4; ++i)
#pragma unroll
    for (int j = 0; j < 4; ++j) acc[i][j] = zero;

  const int rbase = (lane >> 4) * 4, cbase = lane & 15;

  for (int tau = 0; tau < T; ++tau) {
    __syncthreads();               // slice tau staged; prior reads of other buf done
    if (tau + 1 < T) {
      const int co = wid * 2;
      char* dst = WsB + ((tau + 1) & 1) * 8192;
      const char* src = Wb + (long)(tau + 1) * 8192;
      gload_lds16(src + co * 1024 + lane * 16, dst + co * 1024);
      gload_lds16(src + (co + 1) * 1024 + lane * 16, dst + (co + 1) * 1024);
    }
    const int ks = tau & 7;
    const char* Wc = WsB + (tau & 1) * 8192;
    bf16x8_t af[4], bv[4];
#pragma unroll
    for (int i = 0; i < 4; ++i)
      af[i] = *(const bf16x8_t*)(AsB + abase[i] + ((((ks << 2) | kslot) ^ akey[i]) << 4));
#pragma unroll
    for (int i = 0; i < 4; ++i) bv[i] = *(const bf16x8_t*)(Wc + boff[i]);
#pragma unroll
    for (int mi = 0; mi < 4; ++mi)
#pragma unroll
      for (int ni = 0; ni < 4; ++ni)
        acc[mi][ni] = __builtin_amdgcn_mfma_f32_16x16x32_bf16(af[mi], bv[ni], acc[mi][ni], 0, 0, 0);

    if (ks == KS - 1) {
      const int np = tau >> 3;
#pragma unroll
      for (int mi = 0; mi < 4; ++mi) {
#pragma unroll
        for (int ni = 0; ni < 4; ++ni) {
          const int col = np * 128 + wc + ni * 16 + cbase;
#pragma unroll
          for (int j = 0; j < 4; ++j) {
            const long row = m0 + wr + mi * 16 + rbase + j;
            float v = acc[mi][ni][j];
            float o;
            if constexpr (MODE == 1) {
              if (col < 64)       o = tanhf(v);
              else if (col < 128) o = v;
              else if (col < 384) { float s = v + b1[col - 128]; o = 1.f / (1.f + expf(-s)); }
              else                o = v + b2[col - 384];
            } else {
              float s = v + b1[col];
              o = 0.5f * s * (1.f + erff(s * 0.70710678118654752f));
            }
            outp[row * N + col] = f2bf(o);
          }
          acc[mi][ni] = zero;
        }
      }
    }
  }
}

// ========== G2: C-mix GEMM (R4/R5-proven shape): x += ys*g + dt*(1-g), x bf16 RMW ==========
__global__ __launch_bounds__(256)
void gemm_cmix(const ushort* __restrict__ A, const ushort* __restrict__ W,
               const ushort* __restrict__ zgd, ushort* __restrict__ x) {
  constexpr int K = 64;
  __shared__ __align__(16) ushort As[128 * 32];
  __shared__ __align__(16) ushort Ws[128 * 32];

  const int t = threadIdx.x, lane = t & 63, wid = t >> 6;
  const long m0 = (long)blockIdx.x * 128;
  const int n0 = blockIdx.y * 128;
  const int wr = (wid >> 1) * 64, wc = (wid & 1) * 64;
  const int c0 = wid * 2;
  const int r0 = c0 * 16 + (lane >> 2), r1 = r0 + 16;
  const int cb0 = (((lane & 3) ^ swzkey(r0)) << 4);
  const int cb1 = (((lane & 3) ^ swzkey(r1)) << 4);
  const char* Ab = (const char*)A;
  const char* Wb = (const char*)W;
  constexpr long K2 = (long)K * 2;

  const int krow = lane & 15, kslot = lane >> 4;
  int aoff[4], boff[4];
#pragma unroll
  for (int i = 0; i < 4; ++i) {
    int ar = wr + i * 16 + krow;
    aoff[i] = ar * 64 + ((kslot ^ swzkey(ar)) << 4);
    int br = wc + i * 16 + krow;
    boff[i] = br * 64 + ((kslot ^ swzkey(br)) << 4);
  }

  const f32x4_t zero = {0.f, 0.f, 0.f, 0.f};
  f32x4_t acc[4][4];
#pragma unroll
  for (int i = 0; i < 4; ++i)
#pragma unroll
    for (int j = 0; j < 4; ++j) acc[i][j] = zero;

  for (int k0 = 0; k0 < K; k0 += 32) {
    const long kb = (long)k0 * 2;
    gload_lds16(Ab + (m0 + r0) * K2 + kb + cb0, (char*)As + c0 * 1024);
    gload_lds16(Ab + (m0 + r1) * K2 + kb + cb1, (char*)As + c0 * 1024 + 1024);
    gload_lds16(Wb + (long)(n0 + r0) * K2 + kb + cb0, (char*)Ws + c0 * 1024);
    gload_lds16(Wb + (long)(n0 + r1) * K2 + kb + cb1, (char*)Ws + c0 * 1024 + 1024);
    __syncthreads();

    bf16x8_t af[4], bv[4];
#pragma unroll
    for (int i = 0; i < 4; ++i) af[i] = *(const bf16x8_t*)((const char*)As + aoff[i]);
#pragma unroll
    for (int i = 0; i < 4; ++i) bv[i] = *(const bf16x8_t*)((const char*)Ws + boff[i]);
#pragma unroll
    for (int mi = 0; mi < 4; ++mi)
#pragma unroll
      for (int ni = 0; ni < 4; ++ni)
        acc[mi][ni] = __builtin_amdgcn_mfma_f32_16x16x32_bf16(af[mi], bv[ni], acc[mi][ni], 0, 0, 0);
    __syncthreads();
  }

  const int rbase = (lane >> 4) * 4;
  const int cbase = lane & 15;
#pragma unroll
  for (int mi = 0; mi < 4; ++mi) {
#pragma unroll
    for (int ni = 0; ni < 4; ++ni) {
      const int col = n0 + wc + ni * 16 + cbase;
#pragma unroll
      for (int j = 0; j < 4; ++j) {
        const long row = m0 + wr + mi * 16 + rbase + j;
        float v = acc[mi][ni][j];
        float gv = bf2f(zgd[row * 640 + 128 + col]);
        float dv = bf2f(zgd[row * 640 + 384 + col]);
        float xo = bf2f(x[row * 256 + col]);
        x[row * 256 + col] = f2bf(xo + v * gv + dv * (1.f - gv));
      }
    }
  }
}

// ========== G3: N=256 full-row GEMM with fused residual + LayerNorm (x bf16) ==========
// MODE 0: xnew = v + b1[col]            MODE 3: xnew = x[row,col] + v + b1[col]
template <int K, int MODE>
__global__ __launch_bounds__(512)
void gemm_ln(const ushort* __restrict__ A, const ushort* __restrict__ W,
             const float* __restrict__ b1, ushort* __restrict__ x,
             const float* __restrict__ lng, const float* __restrict__ lnb,
             ushort* __restrict__ y, int writex) {
  constexpr int KS = K / 32;
  __shared__ __align__(16) char WsB[2 * 16384];
  __shared__ __align__(16) char AsB[2 * 8192];
  __shared__ float lsum4[128][4], lsq4[128][4];

  const int t = threadIdx.x, lane = t & 63, wid = t >> 6;
  const int wr = (wid >> 2) * 64, wc = (wid & 3) * 64;
  const int lr = lane >> 2, lc = lane & 3;
  const int ra = wid * 16 + lr;
  const int saA = (lc ^ swzkey(ra)) << 4;
  const int rw0 = wid * 32 + lr, rw1 = rw0 + 16;
  const int sw0 = (lc ^ swzkey(rw0)) << 4;
  const int sw1 = (lc ^ swzkey(rw1)) << 4;
  const char* Ab = (const char*)A;
  const char* Wb = (const char*)W;
  constexpr long K2 = (long)K * 2;
  const long m0 = (long)blockIdx.x * 128;

  gload_lds16(Wb + (long)rw0 * K2 + sw0, WsB + wid * 2048);
  gload_lds16(Wb + (long)rw1 * K2 + sw1, WsB + wid * 2048 + 1024);
  gload_lds16(Ab + (m0 + ra) * K2 + saA, AsB + wid * 1024);

  const int krow = lane & 15, kslot = lane >> 4;
  int aoff[4], boff[4];
#pragma unroll
  for (int i = 0; i < 4; ++i) {
    int ar = wr + i * 16 + krow;
    aoff[i] = ar * 64 + ((kslot ^ swzkey(ar)) << 4);
    int br = wc + i * 16 + krow;
    boff[i] = br * 64 + ((kslot ^ swzkey(br)) << 4);
  }

  const f32x4_t zero = {0.f, 0.f, 0.f, 0.f};
  f32x4_t acc[4][4];
#pragma unroll
  for (int i = 0; i < 4; ++i)
#pragma unroll
    for (int j = 0; j < 4; ++j) acc[i][j] = zero;

  for (int tau = 0; tau < KS; ++tau) {
    __syncthreads();
    if (tau + 1 < KS) {
      const long kb = (long)(tau + 1) * 64;
      gload_lds16(Ab + (m0 + ra) * K2 + kb + saA, AsB + ((tau + 1) & 1) * 8192 + wid * 1024);
      char* wd = WsB + ((tau + 1) & 1) * 16384 + wid * 2048;
      gload_lds16(Wb + (long)rw0 * K2 + kb + sw0, wd);
      gload_lds16(Wb + (long)rw1 * K2 + kb + sw1, wd + 1024);
    }
    const char* Ac = AsB + (tau & 1) * 8192;
    const char* Wc = WsB + (tau & 1) * 16384;
    bf16x8_t af[4], bv[4];
#pragma unroll
    for (int i = 0; i < 4; ++i) af[i] = *(const bf16x8_t*)(Ac + aoff[i]);
#pragma unroll
    for (int i = 0; i < 4; ++i) bv[i] = *(const bf16x8_t*)(Wc + boff[i]);
#pragma unroll
    for (int mi = 0; mi < 4; ++mi)
#pragma unroll
      for (int ni = 0; ni < 4; ++ni)
        acc[mi][ni] = __builtin_amdgcn_mfma_f32_16x16x32_bf16(af[mi], bv[ni], acc[mi][ni], 0, 0, 0);
  }

  const int rbase = (lane >> 4) * 4;
  const int cbase = lane & 15;
#pragma unroll
  for (int mi = 0; mi < 4; ++mi) {
#pragma unroll
    for (int ni = 0; ni < 4; ++ni) {
      const int col = wc + ni * 16 + cbase;
#pragma unroll
      for (int j = 0; j < 4; ++j) {
        const long row = m0 + wr + mi * 16 + rbase + j;
        float v = acc[mi][ni][j] + b1[col];
        if constexpr (MODE == 3) v += bf2f(x[row * 256 + col]);
        acc[mi][ni][j] = v;
      }
    }
  }
#pragma unroll
  for (int mi = 0; mi < 4; ++mi) {
#pragma unroll
    for (int j = 0; j < 4; ++j) {
      float ps = 0.f, pq = 0.f;
#pragma unroll
      for (int ni = 0; ni < 4; ++ni) { float v = acc[mi][ni][j]; ps += v; pq += v * v; }
#pragma unroll
      for (int off = 1; off < 16; off <<= 1) {
        ps += __shfl_xor(ps, off, 64);
        pq += __shfl_xor(pq, off, 64);
      }
      if ((lane & 15) == 0) {
        int r = wr + mi * 16 + (lane >> 4) * 4 + j;
        lsum4[r][wid & 3] = ps;
        lsq4[r][wid & 3] = pq;
      }
    }
  }
  __syncthreads();
#pragma unroll
  for (int mi = 0; mi < 4; ++mi) {
#pragma unroll
    for (int j = 0; j < 4; ++j) {
      const int r = wr + mi * 16 + rbase + j;
      const float s = lsum4[r][0] + lsum4[r][1] + lsum4[r][2] + lsum4[r][3];
      const float q = lsq4[r][0] + lsq4[r][1] + lsq4[r][2] + lsq4[r][3];
      const float mean = s * (1.f / 256.f);
      const float rstd = rsqrtf(q * (1.f / 256.f) - mean * mean + 1e-5f);
      const long row = m0 + r;
#pragma unroll
      for (int ni = 0; ni < 4; ++ni) {
        const int col = wc + ni * 16 + cbase;
        const float v = acc[mi][ni][j];
        if (writex) x[row * 256 + col] = f2bf(v);
        y[row * 256 + col] = f2bf((v - mean) * rstd * lng[col] + lnb[col]);
      }
    }
  }
}

// ---------------- LayerNorm: bf16 in -> bf16 out ----------------
__global__ __launch_bounds__(256)
void ln_kernel(const ushort* __restrict__ x, const float* __restrict__ g,
               const float* __restrict__ b, ushort* __restrict__ y) {
  const int lane = threadIdx.x & 63;
  const long row = (long)blockIdx.x * 4 + (threadIdx.x >> 6);
  const ushort4 u = *(const ushort4*)(x + row * 256 + lane * 4);
  float v0 = bf2f(u.x), v1 = bf2f(u.y), v2 = bf2f(u.z), v3 = bf2f(u.w);
  float s = v0 + v1 + v2 + v3;
  float q = v0 * v0 + v1 * v1 + v2 * v2 + v3 * v3;
#pragma unroll
  for (int off = 32; off > 0; off >>= 1) {
    s += __shfl_xor(s, off, 64);
    q += __shfl_xor(q, off, 64);
  }
  const float mean = s * (1.f / 256.f);
  const float rstd = rsqrtf(q * (1.f / 256.f) - mean * mean + 1e-5f);
  const int c = lane * 4;
  const float4 gv = *(const float4*)(g + c);
  const float4 bv = *(const float4*)(b + c);
  ushort4 o;
  o.x = f2bf((v0 - mean) * rstd * gv.x + bv.x);
  o.y = f2bf((v1 - mean) * rstd * gv.y + bv.y);
  o.z = f2bf((v2 - mean) * rstd * gv.z + bv.z);
  o.w = f2bf((v3 - mean) * rstd * gv.w + bv.w);
  *(ushort4*)(y + row * 256 + c) = o;
}

// ---------------- scan ----------------
__global__ __launch_bounds__(256)
void scan_kernel(const ushort* __restrict__ z, ushort* __restrict__ hs) {
  const long tid = (long)blockIdx.x * 256 + threadIdx.x;
  const long b = tid >> 6;
  const int d = tid & 63;
  const ushort* zb = z + b * (16 * 640);
  ushort* hb = hs + b * (16 * 64);
  float h = 0.f;
#pragma unroll
  for (int s = 0; s < 16; ++s) {
    float a  = bf2f(zb[s * 640 + d]);
    float bt = bf2f(zb[s * 640 + 64 + d]);
    h = fmaf(a, h, bt);
    hb[s * 64 + d] = f2bf(h);
  }
}

// ---------------- head ----------------
__global__ __launch_bounds__(256)
void head_kernel(const ushort* __restrict__ yin, const float* __restrict__ attw,
                 const float* __restrict__ ow, const float* __restrict__ ob,
                 const float* __restrict__ cw, const float* __restrict__ cb,
                 float* __restrict__ out) {
  __shared__ float xf[16][256];
  __shared__ float lg[16], aw[16];
  __shared__ float vs[256], o1[128], lgc[40], lse[1];
  const int t = threadIdx.x, lane = t & 63, wid = t >> 6;
  const ushort* yb = yin + (long)blockIdx.x * 16 * 256;

  for (int r = wid; r < 16; r += 4) {
    ushort4 u = *(const ushort4*)(yb + r * 256 + lane * 4);
    int c = lane * 4;
    xf[r][c + 0] = bf2f(u.x);
    xf[r][c + 1] = bf2f(u.y);
    xf[r][c + 2] = bf2f(u.z);
    xf[r][c + 3] = bf2f(u.w);
  }
  __syncthreads();

  for (int r = wid; r < 16; r += 4) {
    const float* wv = attw + (r == 0 ? 0 : 256);
    int c = lane * 4;
    float s = xf[r][c] * wv[c] + xf[r][c + 1] * wv[c + 1] +
              xf[r][c + 2] * wv[c + 2] + xf[r][c + 3] * wv[c + 3];
#pragma unroll
    for (int off = 32; off > 0; off >>= 1) s += __shfl_xor(s, off, 64);
    if (lane == 0) lg[r] = s;
  }
  __syncthreads();

  if (t == 0) {
    float mx = -1e30f;
    for (int s2 = 1; s2 < 16; ++s2) mx = fmaxf(mx, lg[s2]);
    float den = 0.f;
    for (int s2 = 1; s2 < 16; ++s2) { float e = expf(lg[s2] - mx); aw[s2] = e; den += e; }
    float inv = 1.f / den;
    for (int s2 = 1; s2 < 16; ++s2) aw[s2] *= inv;
  }
  __syncthreads();

  float vh = xf[0][t];
  for (int s2 = 1; s2 < 16; ++s2) vh += aw[s2] * xf[s2][t];
  vs[t] = vh;
  __syncthreads();

  if (t < 128) {
    float s = ob[t];
    const float* w = ow + t * 256;
    for (int h2 = 0; h2 < 256; ++h2) s += w[h2] * vs[h2];
    o1[t] = fmaxf(s, 0.f);
  }
  __syncthreads();

  if (t < 40) {
    float s = cb[t];
    const float* w = cw + t * 128;
    for (int j = 0; j < 128; ++j) s += w[j] * o1[j];
    lgc[t] = s;
  }
  __syncthreads();

  if (t == 0) {
    float mx = -1e30f;
    for (int c2 = 0; c2 < 40; ++c2) mx = fmaxf(mx, lgc[c2]);
    float den = 0.f;
    for (int c2 = 0; c2 < 40; ++c2) den += expf(lgc[c2] - mx);
    lse[0] = mx + logf(den);
  }
  __syncthreads();
  if (t < 40) out[(long)blockIdx.x * 40 + t] = lgc[t] - lse[0];
}

// ---------------- host ----------------
extern "C" void kernel_launch(void* const* d_in, const int* in_sizes, int n_in,
                              void* d_out, int out_size, void* d_ws, size_t ws_size,
                              hipStream_t stream) {
  const float* data   = (const float*)d_in[0];
  const float* in_w   = (const float*)d_in[1];
  const float* in_b   = (const float*)d_in[2];
  const float* norm_g = (const float*)d_in[3];
  const float* norm_b = (const float*)d_in[4];
  const float* A_w    = (const float*)d_in[5];
  const float* B_w    = (const float*)d_in[6];
  const float* C_w    = (const float*)d_in[7];
  const float* D_w    = (const float*)d_in[8];
  const float* D_b    = (const float*)d_in[9];
  const float* gate_w = (const float*)d_in[10];
  const float* gate_b = (const float*)d_in[11];
  const float* ffn_w1 = (const float*)d_in[12];
  const float* ffn_b1 = (const float*)d_in[13];
  const float* ffn_w2 = (const float*)d_in[14];
  const float* ffn_b2 = (const float*)d_in[15];
  const float* fln_g  = (const float*)d_in[16];
  const float* fln_b  = (const float*)d_in[17];
  const float* out_w  = (const float*)d_in[18];
  const float* out_b  = (const float*)d_in[19];
  const float* cls_w  = (const float*)d_in[20];
  const float* cls_b  = (const float*)d_in[21];
  const float* attn_w = (const float*)d_in[22];
  const float* attn_b = (const float*)d_in[23];
  (void)in_sizes; (void)n_in; (void)out_size; (void)ws_size; (void)attn_b;

  char* ws = (char*)d_ws;
  ushort* x     = (ushort*)(ws + 0);           // 131072*256*2  =  67108864
  ushort* y     = (ushort*)(ws + 67108864);    // 131072*256*2  =  67108864
  ushort* z     = (ushort*)(ws + 134217728);   // 131072*640*2  = 167772160 (reused: datab, ffn1 t)
  ushort* hs    = (ushort*)(ws + 301989888);   // 131072*64*2   =  16777216
  ushort* wcat  = (ushort*)(ws + 318767104);   // 6*640*256*2   =   1966080
  ushort* inwb  = (ushort*)(ws + 320733184);   // 256*512*2     =    262144
  ushort* w1b   = (ushort*)(ws + 320995328);   // 6*512*256*2   =   1572864
  ushort* w2b   = (ushort*)(ws + 322568192);   // 6*256*512*2   =   1572864
  ushort* cwb   = (ushort*)(ws + 324141056);   // 6*256*64*2    =    196608
  ushort* wcatk = (ushort*)(ws + 324337664);   // 6*640*256*2   =   1966080 (k-sliced)
  ushort* w1k   = (ushort*)(ws + 326303744);   // 6*512*256*2   =   1572864 (k-sliced)
  ushort* datab = z;                           // consumed by input proj before z written

  cvt_kernel<<<512, 256, 0, stream>>>(in_w, inwb, 131072);
  cvt_kernel<<<3072, 256, 0, stream>>>(ffn_w1, w1b, 786432);
  cvt_kernel<<<3072, 256, 0, stream>>>(ffn_w2, w2b, 786432);
  cvt_kernel<<<384, 256, 0, stream>>>(C_w, cwb, 98304);
  build_wcat<<<3840, 256, 0, stream>>>(A_w, B_w, gate_w, D_w, wcat);
  repack_ks<<<3840, 256, 0, stream>>>(wcat, wcatk, 640, 6);
  repack_ks<<<3072, 256, 0, stream>>>(w1b, w1k, 512, 6);
  cvt4_kernel<<<65536, 256, 0, stream>>>(data, datab, 16777216);

  // input proj + fused LN(layer0): x(bf16), y
  gemm_ln<512, 0><<<dim3(1024), 512, 0, stream>>>(
      datab, inwb, in_b, x, norm_g, norm_b, y, 1);

  for (int l = 0; l < 6; ++l) {
    gemm_ws<5, 1><<<1024, 256, 0, stream>>>(
        y, wcatk + (size_t)l * 640 * 256, gate_b + l * 256, D_b + l * 256, z);
    scan_kernel<<<2048, 256, 0, stream>>>(z, hs);
    gemm_cmix<<<dim3(1024, 2), 256, 0, stream>>>(
        hs, cwb + (size_t)l * 256 * 64, z, x);
    ln_kernel<<<32768, 256, 0, stream>>>(x, norm_g + l * 256, norm_b + l * 256, y);
    gemm_ws<4, 2><<<1024, 256, 0, stream>>>(
        y, w1k + (size_t)l * 512 * 256, ffn_b1 + l * 512, nullptr, z);
    const float* lg2 = (l < 5) ? (norm_g + (l + 1) * 256) : fln_g;
    const float* lb2 = (l < 5) ? (norm_b + (l + 1) * 256) : fln_b;
    gemm_ln<512, 3><<<dim3(1024), 512, 0, stream>>>(
        z, w2b + (size_t)l * 256 * 512, ffn_b2 + l * 256, x, lg2, lb2, y, (l < 5) ? 1 : 0);
  }

  head_kernel<<<8192, 256, 0, stream>>>(y, attn_w, out_w, out_b, cls_w, cls_b, (float*)d_out);
}

// Round 9
// 2967.416 us; speedup vs baseline: 1.8937x; 1.1304x over previous
//
#include <hip/hip_runtime.h>

typedef __attribute__((ext_vector_type(8))) short bf16x8_t;
typedef __attribute__((ext_vector_type(4))) float f32x4_t;

__device__ __forceinline__ ushort f2bf(float x) {
  union { float f; unsigned u; } a; a.f = x;
  unsigned r = a.u + 0x7fffu + ((a.u >> 16) & 1u);
  return (ushort)(r >> 16);
}
__device__ __forceinline__ float bf2f(ushort s) {
  union { unsigned u; float f; } a; a.u = ((unsigned)s) << 16;
  return a.f;
}
__device__ __forceinline__ void gload_lds16(const void* g, void* l) {
  __builtin_amdgcn_global_load_lds(
      (const __attribute__((address_space(1))) unsigned int*)g,
      (__attribute__((address_space(3))) unsigned int*)l, 16, 0, 0);
}
__device__ __forceinline__ int swzkey(int r) { return ((r >> 2) ^ r) & 3; }

// ---------------- weight conversion ----------------
__global__ void cvt_kernel(const float* __restrict__ s, ushort* __restrict__ d, int n) {
  int i = blockIdx.x * 256 + threadIdx.x;
  if (i < n) d[i] = f2bf(s[i]);
}

__global__ void cvt4_kernel(const float* __restrict__ s, ushort* __restrict__ d, long n4) {
  long i = (long)blockIdx.x * 256 + threadIdx.x;
  if (i < n4) {
    float4 v = ((const float4*)s)[i];
    ushort4 o;
    o.x = f2bf(v.x); o.y = f2bf(v.y); o.z = f2bf(v.z); o.w = f2bf(v.w);
    ((ushort4*)d)[i] = o;
  }
}

// Wcat[l][r][c], r: 0-63 A_w, 64-127 B_w, 128-383 gate_w, 384-639 D_w
__global__ void build_wcat(const float* __restrict__ Aw, const float* __restrict__ Bw,
                           const float* __restrict__ gw, const float* __restrict__ Dw,
                           ushort* __restrict__ out) {
  int i = blockIdx.x * 256 + threadIdx.x;
  if (i >= 6 * 640 * 256) return;
  int l = i / (640 * 256), r = (i / 256) % 640, c = i % 256;
  float v;
  if (r < 64)        v = Aw[((l * 64 + r) * 256) + c];
  else if (r < 128)  v = Bw[((l * 64 + (r - 64)) * 256) + c];
  else if (r < 384)  v = gw[((l * 256 + (r - 128)) * 256) + c];
  else               v = Dw[((l * 256 + (r - 384)) * 256) + c];
  out[i] = f2bf(v);
}

// repack row-major [N][256] bf16 -> k-sliced [p][ks][r][s][e]; slice = 8KB contiguous
__global__ void repack_ks(const ushort* __restrict__ src, ushort* __restrict__ dst,
                          int N, int nmat) {
  const int perMat = N * 256;
  const long total = (long)nmat * perMat;
  const long i = (long)blockIdx.x * 256 + threadIdx.x;
  if (i >= total) return;
  const int m = (int)(i / perMat);
  const int idx = (int)(i % perMat);
  const int p = idx >> 15;
  const int idx2 = idx & 32767;
  const int ks = idx2 >> 12;
  const int r = (idx2 >> 5) & 127;
  const int s = (idx2 >> 3) & 3;
  const int e = idx2 & 7;
  const int k = ks * 32 + ((s ^ ((r >> 1) & 3)) << 3) + e;
  dst[(long)m * perMat + idx] = src[(long)m * perMat + (p * 128 + r) * 256 + k];
}

// ========== G1: A-stationary GEMM, k-sliced W. K=256.
// MODE 1 (wcat): np==0 -> zab row-major [M][128] (tanh on col<64);
//                np>=1 -> packed zp ((mblk*4+np-1)*16384 + chunk*256 + lane*4), ushort4
//                sigmoid(v+b1) for np in {1,2}, v+b2 for np in {3,4}
// MODE 2 (ffn1): row-major t [M][512], gelu(v+b1)   [control arm: writes unchanged]
template <int NP, int MODE>
__global__ __launch_bounds__(256, 2)
void gemm_ws(const ushort* __restrict__ A, const ushort* __restrict__ Wks,
             const float* __restrict__ b1, const float* __restrict__ b2,
             ushort* __restrict__ outp, ushort* __restrict__ zab,
             ushort* __restrict__ zp) {
  constexpr int KS = 8;
  constexpr int N = NP * 128;
  constexpr int T = NP * KS;
  __shared__ __align__(16) char AsB[128 * 512];
  __shared__ __align__(16) char WsB[2 * 8192];

  const int t = threadIdx.x, lane = t & 63, wid = t >> 6;
  const long m0 = (long)blockIdx.x * 128;
  const int wr = (wid >> 1) * 64, wc = (wid & 1) * 64;
  const char* Ab = (const char*)A;
  const char* Wb = (const char*)Wks;

  {
    const int arow = lane >> 5;
    const int aps  = lane & 31;
#pragma unroll
    for (int j = 0; j < 16; ++j) {
      const int r = j * 8 + wid * 2 + arow;
      gload_lds16(Ab + (m0 + r) * 512 + (long)((aps ^ (r & 7)) << 4),
                  AsB + (j * 8 + wid * 2) * 512);
    }
  }
  {
    const int co = wid * 2;
    gload_lds16(Wb + co * 1024 + lane * 16, WsB + co * 1024);
    gload_lds16(Wb + (co + 1) * 1024 + lane * 16, WsB + (co + 1) * 1024);
  }

  const int krow = lane & 15, kslot = lane >> 4;
  int abase[4], akey[4], boff[4];
#pragma unroll
  for (int i = 0; i < 4; ++i) {
    const int ar = wr + i * 16 + krow;
    abase[i] = ar * 512;
    akey[i] = ar & 7;
    const int br = wc + i * 16 + krow;
    boff[i] = br * 64 + ((kslot ^ ((br >> 1) & 3)) << 4);
  }

  const f32x4_t zero = {0.f, 0.f, 0.f, 0.f};
  f32x4_t acc[4][4];
#pragma unroll
  for (int i = 0; i < 4; ++i)
#pragma unroll
    for (int j = 0; j < 4; ++j) acc[i][j] = zero;

  const int rbase = (lane >> 4) * 4, cbase = lane & 15;

  for (int tau = 0; tau < T; ++tau) {
    __syncthreads();
    if (tau + 1 < T) {
      const int co = wid * 2;
      char* dst = WsB + ((tau + 1) & 1) * 8192;
      const char* src = Wb + (long)(tau + 1) * 8192;
      gload_lds16(src + co * 1024 + lane * 16, dst + co * 1024);
      gload_lds16(src + (co + 1) * 1024 + lane * 16, dst + (co + 1) * 1024);
    }
    const int ks = tau & 7;
    const char* Wc = WsB + (tau & 1) * 8192;
    bf16x8_t af[4], bv[4];
#pragma unroll
    for (int i = 0; i < 4; ++i)
      af[i] = *(const bf16x8_t*)(AsB + abase[i] + ((((ks << 2) | kslot) ^ akey[i]) << 4));
#pragma unroll
    for (int i = 0; i < 4; ++i) bv[i] = *(const bf16x8_t*)(Wc + boff[i]);
#pragma unroll
    for (int mi = 0; mi < 4; ++mi)
#pragma unroll
      for (int ni = 0; ni < 4; ++ni)
        acc[mi][ni] = __builtin_amdgcn_mfma_f32_16x16x32_bf16(af[mi], bv[ni], acc[mi][ni], 0, 0, 0);

    if (ks == KS - 1) {
      const int np = tau >> 3;
      if constexpr (MODE == 2) {
#pragma unroll
        for (int mi = 0; mi < 4; ++mi) {
#pragma unroll
          for (int ni = 0; ni < 4; ++ni) {
            const int col = np * 128 + wc + ni * 16 + cbase;
#pragma unroll
            for (int j = 0; j < 4; ++j) {
              const long row = m0 + wr + mi * 16 + rbase + j;
              float s = acc[mi][ni][j] + b1[col];
              float o = 0.5f * s * (1.f + erff(s * 0.70710678118654752f));
              outp[row * N + col] = f2bf(o);
            }
            acc[mi][ni] = zero;
          }
        }
      } else if (np == 0) {
#pragma unroll
        for (int mi = 0; mi < 4; ++mi) {
#pragma unroll
          for (int ni = 0; ni < 4; ++ni) {
            const int col = wc + ni * 16 + cbase;
#pragma unroll
            for (int j = 0; j < 4; ++j) {
              const long row = m0 + wr + mi * 16 + rbase + j;
              float v = acc[mi][ni][j];
              zab[row * 128 + col] = f2bf(col < 64 ? tanhf(v) : v);
            }
            acc[mi][ni] = zero;
          }
        }
      } else {
        const long pb = ((long)blockIdx.x * 4 + (np - 1)) * 16384;
#pragma unroll
        for (int mi = 0; mi < 4; ++mi) {
#pragma unroll
          for (int ni = 0; ni < 4; ++ni) {
            const int colw = wc + ni * 16 + cbase;
            ushort4 o4;
#pragma unroll
            for (int j = 0; j < 4; ++j) {
              float v = acc[mi][ni][j];
              float o;
              if (np <= 2) { float s = v + b1[(np - 1) * 128 + colw]; o = 1.f / (1.f + expf(-s)); }
              else         { o = v + b2[(np - 3) * 128 + colw]; }
              if (j == 0) o4.x = f2bf(o);
              else if (j == 1) o4.y = f2bf(o);
              else if (j == 2) o4.z = f2bf(o);
              else o4.w = f2bf(o);
            }
            *(ushort4*)(zp + pb + (wid * 16 + mi * 4 + ni) * 256 + lane * 4) = o4;
            acc[mi][ni] = zero;
          }
        }
      }
    }
  }
}

// ========== G2: C-mix GEMM: xP += ys*g + dt*(1-g); packed g/dt + packed x ==========
__global__ __launch_bounds__(256)
void gemm_cmix(const ushort* __restrict__ A, const ushort* __restrict__ W,
               const ushort* __restrict__ zp, ushort* __restrict__ xP) {
  constexpr int K = 64;
  __shared__ __align__(16) ushort As[128 * 32];
  __shared__ __align__(16) ushort Ws[128 * 32];

  const int t = threadIdx.x, lane = t & 63, wid = t >> 6;
  const long m0 = (long)blockIdx.x * 128;
  const int n0 = blockIdx.y * 128;
  const int wr = (wid >> 1) * 64, wc = (wid & 1) * 64;
  const int c0 = wid * 2;
  const int r0 = c0 * 16 + (lane >> 2), r1 = r0 + 16;
  const int cb0 = (((lane & 3) ^ swzkey(r0)) << 4);
  const int cb1 = (((lane & 3) ^ swzkey(r1)) << 4);
  const char* Ab = (const char*)A;
  const char* Wb = (const char*)W;
  constexpr long K2 = (long)K * 2;

  const int krow = lane & 15, kslot = lane >> 4;
  int aoff[4], boff[4];
#pragma unroll
  for (int i = 0; i < 4; ++i) {
    int ar = wr + i * 16 + krow;
    aoff[i] = ar * 64 + ((kslot ^ swzkey(ar)) << 4);
    int br = wc + i * 16 + krow;
    boff[i] = br * 64 + ((kslot ^ swzkey(br)) << 4);
  }

  const f32x4_t zero = {0.f, 0.f, 0.f, 0.f};
  f32x4_t acc[4][4];
#pragma unroll
  for (int i = 0; i < 4; ++i)
#pragma unroll
    for (int j = 0; j < 4; ++j) acc[i][j] = zero;

  for (int k0 = 0; k0 < K; k0 += 32) {
    const long kb = (long)k0 * 2;
    gload_lds16(Ab + (m0 + r0) * K2 + kb + cb0, (char*)As + c0 * 1024);
    gload_lds16(Ab + (m0 + r1) * K2 + kb + cb1, (char*)As + c0 * 1024 + 1024);
    gload_lds16(Wb + (long)(n0 + r0) * K2 + kb + cb0, (char*)Ws + c0 * 1024);
    gload_lds16(Wb + (long)(n0 + r1) * K2 + kb + cb1, (char*)Ws + c0 * 1024 + 1024);
    __syncthreads();

    bf16x8_t af[4], bv[4];
#pragma unroll
    for (int i = 0; i < 4; ++i) af[i] = *(const bf16x8_t*)((const char*)As + aoff[i]);
#pragma unroll
    for (int i = 0; i < 4; ++i) bv[i] = *(const bf16x8_t*)((const char*)Ws + boff[i]);
#pragma unroll
    for (int mi = 0; mi < 4; ++mi)
#pragma unroll
      for (int ni = 0; ni < 4; ++ni)
        acc[mi][ni] = __builtin_amdgcn_mfma_f32_16x16x32_bf16(af[mi], bv[ni], acc[mi][ni], 0, 0, 0);
    __syncthreads();
  }

  // packed epilogue: g panel = blockIdx.y, dt panel = 2+blockIdx.y
  const long gb = ((long)blockIdx.x * 4 + blockIdx.y) * 16384;
  const long db = ((long)blockIdx.x * 4 + 2 + blockIdx.y) * 16384;
  const long xb = (long)blockIdx.x * 32768;
#pragma unroll
  for (int mi = 0; mi < 4; ++mi) {
    const int rq = (wid >> 1) * 4 + mi;
#pragma unroll
    for (int ni = 0; ni < 4; ++ni) {
      const int chunk = (wid * 16 + mi * 4 + ni) * 256 + lane * 4;
      const int cq = blockIdx.y * 8 + (wid & 1) * 4 + ni;
      ushort4 g4 = *(const ushort4*)(zp + gb + chunk);
      ushort4 d4 = *(const ushort4*)(zp + db + chunk);
      ushort4* xa = (ushort4*)(xP + xb + ((rq * 16 + cq) * 64 + lane) * 4);
      ushort4 x4 = *xa;
      ushort4 o4;
      {
        float gv = bf2f(g4.x), dv = bf2f(d4.x);
        o4.x = f2bf(bf2f(x4.x) + acc[mi][ni][0] * gv + dv * (1.f - gv));
        gv = bf2f(g4.y); dv = bf2f(d4.y);
        o4.y = f2bf(bf2f(x4.y) + acc[mi][ni][1] * gv + dv * (1.f - gv));
        gv = bf2f(g4.z); dv = bf2f(d4.z);
        o4.z = f2bf(bf2f(x4.z) + acc[mi][ni][2] * gv + dv * (1.f - gv));
        gv = bf2f(g4.w); dv = bf2f(d4.w);
        o4.w = f2bf(bf2f(x4.w) + acc[mi][ni][3] * gv + dv * (1.f - gv));
      }
      *xa = o4;
    }
  }
}

// ========== G3: N=256 GEMM + fused residual + LayerNorm; x packed, y row-major ==========
// MODE 0: xnew = v + b1[col]            MODE 3: xnew = xP(row,col) + v + b1[col]
template <int K, int MODE>
__global__ __launch_bounds__(512)
void gemm_ln(const ushort* __restrict__ A, const ushort* __restrict__ W,
             const float* __restrict__ b1, ushort* __restrict__ xP,
             const float* __restrict__ lng, const float* __restrict__ lnb,
             ushort* __restrict__ y, int writex) {
  constexpr int KS = K / 32;
  __shared__ __align__(16) char WsB[2 * 16384];
  __shared__ __align__(16) char AsB[2 * 8192];
  __shared__ float lsum4[128][4], lsq4[128][4];

  const int t = threadIdx.x, lane = t & 63, wid = t >> 6;
  const int wr = (wid >> 2) * 64, wc = (wid & 3) * 64;
  const int lr = lane >> 2, lc = lane & 3;
  const int ra = wid * 16 + lr;
  const int saA = (lc ^ swzkey(ra)) << 4;
  const int rw0 = wid * 32 + lr, rw1 = rw0 + 16;
  const int sw0 = (lc ^ swzkey(rw0)) << 4;
  const int sw1 = (lc ^ swzkey(rw1)) << 4;
  const char* Ab = (const char*)A;
  const char* Wb = (const char*)W;
  constexpr long K2 = (long)K * 2;
  const long m0 = (long)blockIdx.x * 128;

  gload_lds16(Wb + (long)rw0 * K2 + sw0, WsB + wid * 2048);
  gload_lds16(Wb + (long)rw1 * K2 + sw1, WsB + wid * 2048 + 1024);
  gload_lds16(Ab + (m0 + ra) * K2 + saA, AsB + wid * 1024);

  const int krow = lane & 15, kslot = lane >> 4;
  int aoff[4], boff[4];
#pragma unroll
  for (int i = 0; i < 4; ++i) {
    int ar = wr + i * 16 + krow;
    aoff[i] = ar * 64 + ((kslot ^ swzkey(ar)) << 4);
    int br = wc + i * 16 + krow;
    boff[i] = br * 64 + ((kslot ^ swzkey(br)) << 4);
  }

  const f32x4_t zero = {0.f, 0.f, 0.f, 0.f};
  f32x4_t acc[4][4];
#pragma unroll
  for (int i = 0; i < 4; ++i)
#pragma unroll
    for (int j = 0; j < 4; ++j) acc[i][j] = zero;

  for (int tau = 0; tau < KS; ++tau) {
    __syncthreads();
    if (tau + 1 < KS) {
      const long kb = (long)(tau + 1) * 64;
      gload_lds16(Ab + (m0 + ra) * K2 + kb + saA, AsB + ((tau + 1) & 1) * 8192 + wid * 1024);
      char* wd = WsB + ((tau + 1) & 1) * 16384 + wid * 2048;
      gload_lds16(Wb + (long)rw0 * K2 + kb + sw0, wd);
      gload_lds16(Wb + (long)rw1 * K2 + kb + sw1, wd + 1024);
    }
    const char* Ac = AsB + (tau & 1) * 8192;
    const char* Wc = WsB + (tau & 1) * 16384;
    bf16x8_t af[4], bv[4];
#pragma unroll
    for (int i = 0; i < 4; ++i) af[i] = *(const bf16x8_t*)(Ac + aoff[i]);
#pragma unroll
    for (int i = 0; i < 4; ++i) bv[i] = *(const bf16x8_t*)(Wc + boff[i]);
#pragma unroll
    for (int mi = 0; mi < 4; ++mi)
#pragma unroll
      for (int ni = 0; ni < 4; ++ni)
        acc[mi][ni] = __builtin_amdgcn_mfma_f32_16x16x32_bf16(af[mi], bv[ni], acc[mi][ni], 0, 0, 0);
  }

  const int rbase = (lane >> 4) * 4;
  const int cbase = lane & 15;
  const long xbB = (long)blockIdx.x * 32768;
  // residual (packed x read for MODE 3)
#pragma unroll
  for (int mi = 0; mi < 4; ++mi) {
    const int rq = (wid >> 2) * 4 + mi;
#pragma unroll
    for (int ni = 0; ni < 4; ++ni) {
      const int col = wc + ni * 16 + cbase;
      const int cq = (wid & 3) * 4 + ni;
      ushort4 x4;
      if constexpr (MODE == 3) x4 = *(const ushort4*)(xP + xbB + ((rq * 16 + cq) * 64 + lane) * 4);
#pragma unroll
      for (int j = 0; j < 4; ++j) {
        float v = acc[mi][ni][j] + b1[col];
        if constexpr (MODE == 3)
          v += bf2f(j == 0 ? x4.x : (j == 1 ? x4.y : (j == 2 ? x4.z : x4.w)));
        acc[mi][ni][j] = v;
      }
    }
  }
#pragma unroll
  for (int mi = 0; mi < 4; ++mi) {
#pragma unroll
    for (int j = 0; j < 4; ++j) {
      float ps = 0.f, pq = 0.f;
#pragma unroll
      for (int ni = 0; ni < 4; ++ni) { float v = acc[mi][ni][j]; ps += v; pq += v * v; }
#pragma unroll
      for (int off = 1; off < 16; off <<= 1) {
        ps += __shfl_xor(ps, off, 64);
        pq += __shfl_xor(pq, off, 64);
      }
      if ((lane & 15) == 0) {
        int r = wr + mi * 16 + (lane >> 4) * 4 + j;
        lsum4[r][wid & 3] = ps;
        lsq4[r][wid & 3] = pq;
      }
    }
  }
  __syncthreads();
#pragma unroll
  for (int mi = 0; mi < 4; ++mi) {
    const int rq = (wid >> 2) * 4 + mi;
#pragma unroll
    for (int ni = 0; ni < 4; ++ni) {
      const int cq = (wid & 3) * 4 + ni;
      if (writex) {
        ushort4 o4;
#pragma unroll
        for (int j = 0; j < 4; ++j) {
          float v = acc[mi][ni][j];
          if (j == 0) o4.x = f2bf(v);
          else if (j == 1) o4.y = f2bf(v);
          else if (j == 2) o4.z = f2bf(v);
          else o4.w = f2bf(v);
        }
        *(ushort4*)(xP + xbB + ((rq * 16 + cq) * 64 + lane) * 4) = o4;
      }
    }
  }
#pragma unroll
  for (int mi = 0; mi < 4; ++mi) {
#pragma unroll
    for (int j = 0; j < 4; ++j) {
      const int r = wr + mi * 16 + rbase + j;
      const float s = lsum4[r][0] + lsum4[r][1] + lsum4[r][2] + lsum4[r][3];
      const float q = lsq4[r][0] + lsq4[r][1] + lsq4[r][2] + lsq4[r][3];
      const float mean = s * (1.f / 256.f);
      const float rstd = rsqrtf(q * (1.f / 256.f) - mean * mean + 1e-5f);
      const long row = m0 + r;
#pragma unroll
      for (int ni = 0; ni < 4; ++ni) {
        const int col = wc + ni * 16 + cbase;
        y[row * 256 + col] = f2bf((acc[mi][ni][j] - mean) * rstd * lng[col] + lnb[col]);
      }
    }
  }
}

// ---------------- LayerNorm from packed x -> row-major y ----------------
__global__ __launch_bounds__(256)
void ln_packed(const ushort* __restrict__ xP, const float* __restrict__ g,
               const float* __restrict__ b, ushort* __restrict__ y) {
  __shared__ float xs[16][260];
  const int t = threadIdx.x, lane = t & 63, w = t >> 6;
  const int cq = t >> 4, ci = t & 15;
  const long base = (long)(blockIdx.x >> 3) * 32768;
  const int rq = blockIdx.x & 7;

#pragma unroll
  for (int ri = 0; ri < 4; ++ri) {
    ushort4 u = *(const ushort4*)(xP + base + (((rq * 16 + cq) * 64 + ((ri << 4) | ci)) << 2));
    const int c = cq * 16 + ci;
    xs[ri * 4 + 0][c] = bf2f(u.x);
    xs[ri * 4 + 1][c] = bf2f(u.y);
    xs[ri * 4 + 2][c] = bf2f(u.z);
    xs[ri * 4 + 3][c] = bf2f(u.w);
  }
  __syncthreads();

#pragma unroll
  for (int rr = 0; rr < 4; ++rr) {
    const int r = w * 4 + rr;
    const int c = lane * 4;
    float v0 = xs[r][c], v1 = xs[r][c + 1], v2 = xs[r][c + 2], v3 = xs[r][c + 3];
    float s = v0 + v1 + v2 + v3;
    float q = v0 * v0 + v1 * v1 + v2 * v2 + v3 * v3;
#pragma unroll
    for (int off = 32; off > 0; off >>= 1) {
      s += __shfl_xor(s, off, 64);
      q += __shfl_xor(q, off, 64);
    }
    const float mean = s * (1.f / 256.f);
    const float rstd = rsqrtf(q * (1.f / 256.f) - mean * mean + 1e-5f);
    ushort4 o;
    o.x = f2bf((v0 - mean) * rstd * g[c + 0] + b[c + 0]);
    o.y = f2bf((v1 - mean) * rstd * g[c + 1] + b[c + 1]);
    o.z = f2bf((v2 - mean) * rstd * g[c + 2] + b[c + 2]);
    o.w = f2bf((v3 - mean) * rstd * g[c + 3] + b[c + 3]);
    *(ushort4*)(y + ((long)blockIdx.x * 16 + r) * 256 + c) = o;
  }
}

// ---------------- scan (reads zab [M][128]) ----------------
__global__ __launch_bounds__(256)
void scan_kernel(const ushort* __restrict__ zab, ushort* __restrict__ hs) {
  const long tid = (long)blockIdx.x * 256 + threadIdx.x;
  const long b = tid >> 6;
  const int d = tid & 63;
  const ushort* zb = zab + b * (16 * 128);
  ushort* hb = hs + b * (16 * 64);
  float h = 0.f;
#pragma unroll
  for (int s = 0; s < 16; ++s) {
    float a  = bf2f(zb[s * 128 + d]);
    float bt = bf2f(zb[s * 128 + 64 + d]);
    h = fmaf(a, h, bt);
    hb[s * 64 + d] = f2bf(h);
  }
}

// ---------------- head ----------------
__global__ __launch_bounds__(256)
void head_kernel(const ushort* __restrict__ yin, const float* __restrict__ attw,
                 const float* __restrict__ ow, const float* __restrict__ ob,
                 const float* __restrict__ cw, const float* __restrict__ cb,
                 float* __restrict__ out) {
  __shared__ float xf[16][256];
  __shared__ float lg[16], aw[16];
  __shared__ float vs[256], o1[128], lgc[40], lse[1];
  const int t = threadIdx.x, lane = t & 63, wid = t >> 6;
  const ushort* yb = yin + (long)blockIdx.x * 16 * 256;

  for (int r = wid; r < 16; r += 4) {
    ushort4 u = *(const ushort4*)(yb + r * 256 + lane * 4);
    int c = lane * 4;
    xf[r][c + 0] = bf2f(u.x);
    xf[r][c + 1] = bf2f(u.y);
    xf[r][c + 2] = bf2f(u.z);
    xf[r][c + 3] = bf2f(u.w);
  }
  __syncthreads();

  for (int r = wid; r < 16; r += 4) {
    const float* wv = attw + (r == 0 ? 0 : 256);
    int c = lane * 4;
    float s = xf[r][c] * wv[c] + xf[r][c + 1] * wv[c + 1] +
              xf[r][c + 2] * wv[c + 2] + xf[r][c + 3] * wv[c + 3];
#pragma unroll
    for (int off = 32; off > 0; off >>= 1) s += __shfl_xor(s, off, 64);
    if (lane == 0) lg[r] = s;
  }
  __syncthreads();

  if (t == 0) {
    float mx = -1e30f;
    for (int s2 = 1; s2 < 16; ++s2) mx = fmaxf(mx, lg[s2]);
    float den = 0.f;
    for (int s2 = 1; s2 < 16; ++s2) { float e = expf(lg[s2] - mx); aw[s2] = e; den += e; }
    float inv = 1.f / den;
    for (int s2 = 1; s2 < 16; ++s2) aw[s2] *= inv;
  }
  __syncthreads();

  float vh = xf[0][t];
  for (int s2 = 1; s2 < 16; ++s2) vh += aw[s2] * xf[s2][t];
  vs[t] = vh;
  __syncthreads();

  if (t < 128) {
    float s = ob[t];
    const float* w = ow + t * 256;
    for (int h2 = 0; h2 < 256; ++h2) s += w[h2] * vs[h2];
    o1[t] = fmaxf(s, 0.f);
  }
  __syncthreads();

  if (t < 40) {
    float s = cb[t];
    const float* w = cw + t * 128;
    for (int j = 0; j < 128; ++j) s += w[j] * o1[j];
    lgc[t] = s;
  }
  __syncthreads();

  if (t == 0) {
    float mx = -1e30f;
    for (int c2 = 0; c2 < 40; ++c2) mx = fmaxf(mx, lgc[c2]);
    float den = 0.f;
    for (int c2 = 0; c2 < 40; ++c2) den += expf(lgc[c2] - mx);
    lse[0] = mx + logf(den);
  }
  __syncthreads();
  if (t < 40) out[(long)blockIdx.x * 40 + t] = lgc[t] - lse[0];
}

// ---------------- host ----------------
extern "C" void kernel_launch(void* const* d_in, const int* in_sizes, int n_in,
                              void* d_out, int out_size, void* d_ws, size_t ws_size,
                              hipStream_t stream) {
  const float* data   = (const float*)d_in[0];
  const float* in_w   = (const float*)d_in[1];
  const float* in_b   = (const float*)d_in[2];
  const float* norm_g = (const float*)d_in[3];
  const float* norm_b = (const float*)d_in[4];
  const float* A_w    = (const float*)d_in[5];
  const float* B_w    = (const float*)d_in[6];
  const float* C_w    = (const float*)d_in[7];
  const float* D_w    = (const float*)d_in[8];
  const float* D_b    = (const float*)d_in[9];
  const float* gate_w = (const float*)d_in[10];
  const float* gate_b = (const float*)d_in[11];
  const float* ffn_w1 = (const float*)d_in[12];
  const float* ffn_b1 = (const float*)d_in[13];
  const float* ffn_w2 = (const float*)d_in[14];
  const float* ffn_b2 = (const float*)d_in[15];
  const float* fln_g  = (const float*)d_in[16];
  const float* fln_b  = (const float*)d_in[17];
  const float* out_w  = (const float*)d_in[18];
  const float* out_b  = (const float*)d_in[19];
  const float* cls_w  = (const float*)d_in[20];
  const float* cls_b  = (const float*)d_in[21];
  const float* attn_w = (const float*)d_in[22];
  const float* attn_b = (const float*)d_in[23];
  (void)in_sizes; (void)n_in; (void)out_size; (void)ws_size; (void)attn_b;

  char* ws = (char*)d_ws;
  ushort* xP    = (ushort*)(ws + 0);           // packed x: 131072*256*2 =  67108864
  ushort* y     = (ushort*)(ws + 67108864);    // 131072*256*2  =  67108864
  ushort* tzp   = (ushort*)(ws + 134217728);   // t / zp / datab: 134217728 (time-shared)
  ushort* zab   = (ushort*)(ws + 268435456);   // 131072*128*2  =  33554432
  ushort* hs    = (ushort*)(ws + 301989888);   // 131072*64*2   =  16777216
  ushort* wcat  = (ushort*)(ws + 318767104);   // 6*640*256*2
  ushort* inwb  = (ushort*)(ws + 320733184);   // 256*512*2
  ushort* w1b   = (ushort*)(ws + 320995328);   // 6*512*256*2
  ushort* w2b   = (ushort*)(ws + 322568192);   // 6*256*512*2
  ushort* cwb   = (ushort*)(ws + 324141056);   // 6*256*64*2
  ushort* wcatk = (ushort*)(ws + 324337664);   // 6*640*256*2 (k-sliced)
  ushort* w1k   = (ushort*)(ws + 326303744);   // 6*512*256*2 (k-sliced)
  ushort* datab = tzp;                         // consumed by input proj before zp written

  cvt_kernel<<<512, 256, 0, stream>>>(in_w, inwb, 131072);
  cvt_kernel<<<3072, 256, 0, stream>>>(ffn_w1, w1b, 786432);
  cvt_kernel<<<3072, 256, 0, stream>>>(ffn_w2, w2b, 786432);
  cvt_kernel<<<384, 256, 0, stream>>>(C_w, cwb, 98304);
  build_wcat<<<3840, 256, 0, stream>>>(A_w, B_w, gate_w, D_w, wcat);
  repack_ks<<<3840, 256, 0, stream>>>(wcat, wcatk, 640, 6);
  repack_ks<<<3072, 256, 0, stream>>>(w1b, w1k, 512, 6);
  cvt4_kernel<<<65536, 256, 0, stream>>>(data, datab, 16777216);

  // input proj + fused LN(layer0): xP (packed), y
  gemm_ln<512, 0><<<dim3(1024), 512, 0, stream>>>(
      datab, inwb, in_b, xP, norm_g, norm_b, y, 1);

  for (int l = 0; l < 6; ++l) {
    gemm_ws<5, 1><<<1024, 256, 0, stream>>>(
        y, wcatk + (size_t)l * 640 * 256, gate_b + l * 256, D_b + l * 256,
        nullptr, zab, tzp);
    scan_kernel<<<2048, 256, 0, stream>>>(zab, hs);
    gemm_cmix<<<dim3(1024, 2), 256, 0, stream>>>(
        hs, cwb + (size_t)l * 256 * 64, tzp, xP);
    ln_packed<<<8192, 256, 0, stream>>>(xP, norm_g + l * 256, norm_b + l * 256, y);
    gemm_ws<4, 2><<<1024, 256, 0, stream>>>(
        y, w1k + (size_t)l * 512 * 256, ffn_b1 + l * 512, nullptr, tzp, nullptr, nullptr);
    const float* lg2 = (l < 5) ? (norm_g + (l + 1) * 256) : fln_g;
    const float* lb2 = (l < 5) ? (norm_b + (l + 1) * 256) : fln_b;
    gemm_ln<512, 3><<<dim3(1024), 512, 0, stream>>>(
        tzp, w2b + (size_t)l * 256 * 512, ffn_b2 + l * 256, xP, lg2, lb2, y, (l < 5) ? 1 : 0);
  }

  head_kernel<<<8192, 256, 0, stream>>>(y, attn_w, out_w, out_b, cls_w, cls_b, (float*)d_out);
}

// Round 10
// 2467.026 us; speedup vs baseline: 2.2778x; 1.2028x over previous
//
#include <hip/hip_runtime.h>

typedef __attribute__((ext_vector_type(8))) short bf16x8_t;
typedef __attribute__((ext_vector_type(4))) float f32x4_t;

__device__ __forceinline__ ushort f2bf(float x) {
  union { float f; unsigned u; } a; a.f = x;
  unsigned r = a.u + 0x7fffu + ((a.u >> 16) & 1u);
  return (ushort)(r >> 16);
}
__device__ __forceinline__ float bf2f(ushort s) {
  union { unsigned u; float f; } a; a.u = ((unsigned)s) << 16;
  return a.f;
}
__device__ __forceinline__ void gload_lds16(const void* g, void* l) {
  __builtin_amdgcn_global_load_lds(
      (const __attribute__((address_space(1))) unsigned int*)g,
      (__attribute__((address_space(3))) unsigned int*)l, 16, 0, 0);
}
__device__ __forceinline__ int swzkey(int r) { return ((r >> 2) ^ r) & 3; }

// ---------------- weight conversion ----------------
__global__ void cvt_kernel(const float* __restrict__ s, ushort* __restrict__ d, int n) {
  int i = blockIdx.x * 256 + threadIdx.x;
  if (i < n) d[i] = f2bf(s[i]);
}

__global__ void cvt4_kernel(const float* __restrict__ s, ushort* __restrict__ d, long n4) {
  long i = (long)blockIdx.x * 256 + threadIdx.x;
  if (i < n4) {
    float4 v = ((const float4*)s)[i];
    ushort4 o;
    o.x = f2bf(v.x); o.y = f2bf(v.y); o.z = f2bf(v.z); o.w = f2bf(v.w);
    ((ushort4*)d)[i] = o;
  }
}

// Wcat[l][r][c], r: 0-63 A_w, 64-127 B_w, 128-383 gate_w, 384-639 D_w
__global__ void build_wcat(const float* __restrict__ Aw, const float* __restrict__ Bw,
                           const float* __restrict__ gw, const float* __restrict__ Dw,
                           ushort* __restrict__ out) {
  int i = blockIdx.x * 256 + threadIdx.x;
  if (i >= 6 * 640 * 256) return;
  int l = i / (640 * 256), r = (i / 256) % 640, c = i % 256;
  float v;
  if (r < 64)        v = Aw[((l * 64 + r) * 256) + c];
  else if (r < 128)  v = Bw[((l * 64 + (r - 64)) * 256) + c];
  else if (r < 384)  v = gw[((l * 256 + (r - 128)) * 256) + c];
  else               v = Dw[((l * 256 + (r - 384)) * 256) + c];
  out[i] = f2bf(v);
}

// repack row-major [N][K] bf16 -> k-sliced [p][ks][r][s][e]; each slice 8KB contiguous.
// physical slot s holds source k-chunk (s ^ ((r>>1)&3)).
__global__ void repack_gen(const ushort* __restrict__ src, ushort* __restrict__ dst,
                           int K, int perMat, long total) {
  const long i = (long)blockIdx.x * 256 + threadIdx.x;
  if (i >= total) return;
  const int m = (int)(i / perMat);
  const int idx = (int)(i % perMat);
  const int slice = idx >> 12;
  const int ksn = K >> 5;
  const int p = slice / ksn, ks = slice - p * ksn;
  const int r = (idx >> 5) & 127;
  const int s = (idx >> 3) & 3;
  const int e = idx & 7;
  const int k = ks * 32 + ((s ^ ((r >> 1) & 3)) << 3) + e;
  dst[(long)m * perMat + idx] = src[(long)m * perMat + (p * 128 + r) * K + k];
}

// ========== FUSED MAMBA LAYER: wcat GEMM + scan + C-mix + combine + LN ==========
// Block = 32 rows = 2 complete batches. y (LN'd x) resident in LDS.
// Streams 44 W slices: wcat panels 0..4 (40) then Cw panels (4).
// Outputs: xP (packed, RMW) and y = LN(xnew) (row-major, in place).
__global__ __launch_bounds__(256, 2)
void mamba_fused(ushort* __restrict__ y, ushort* __restrict__ xP,
                 const ushort* __restrict__ Wk, const ushort* __restrict__ Ck,
                 const float* __restrict__ gb, const float* __restrict__ db,
                 const float* __restrict__ lng, const float* __restrict__ lnb) {
  __shared__ __align__(16) char Ys[16384];       // resident y tile 32x256 (swizzled)
  __shared__ __align__(16) char WsB[16384];      // W slice double buffer
  __shared__ __align__(16) ushort ab[32 * 136];  // a|bt, stride 136 ushorts (272B)
  __shared__ __align__(16) char HsB[4096];       // hs 32x64 (swizzled 128B rows)
  __shared__ float lsum[32][2], lsq[32][2];

  const int t = threadIdx.x, lane = t & 63, wid = t >> 6;
  const long m0 = (long)blockIdx.x * 32;
  const int wr = (wid >> 1) * 16, wc = (wid & 1) * 64;
  const int co = wid * 2;
  const char* yg = (const char*)y;

  // stage resident y tile (16 x 1KB coalesced; swizzled source, linear dest)
  {
    const int r0 = lane >> 5, sl = lane & 31;
#pragma unroll
    for (int jj = 0; jj < 4; ++jj) {
      const int cc = jj * 4 + wid;
      const int r = cc * 2 + r0;
      gload_lds16(yg + (m0 + r) * 512 + ((sl ^ (r & 7)) << 4), Ys + cc * 1024);
    }
  }
  // stage W slice 0
  gload_lds16((const char*)Wk + co * 1024 + lane * 16, WsB + co * 1024);
  gload_lds16((const char*)Wk + (co + 1) * 1024 + lane * 16, WsB + (co + 1) * 1024);

  const int krow = lane & 15, kslot = lane >> 4;
  const int ar = wr + krow;
  const int akey = ar & 7;
  int boff[4];
#pragma unroll
  for (int i = 0; i < 4; ++i) {
    const int br = wc + i * 16 + krow;
    boff[i] = br * 64 + ((kslot ^ ((br >> 1) & 3)) << 4);
  }
  const int rbase = (lane >> 4) * 4, cbase = lane & 15;

  const f32x4_t zero = {0.f, 0.f, 0.f, 0.f};
  f32x4_t acc[4];
#pragma unroll
  for (int i = 0; i < 4; ++i) acc[i] = zero;

  int tau = 0;
  auto sliceptr = [&](int i) -> const char* {
    return (i < 40) ? ((const char*)Wk + (long)i * 8192)
                    : ((const char*)Ck + (long)(i - 40) * 8192);
  };
  auto kstep = [&](const char* Abuf, int rsh, int ks) {
    __syncthreads();
    if (tau + 1 < 44) {
      const char* src = sliceptr(tau + 1);
      char* dst = WsB + ((tau + 1) & 1) * 8192;
      gload_lds16(src + co * 1024 + lane * 16, dst + co * 1024);
      gload_lds16(src + (co + 1) * 1024 + lane * 16, dst + (co + 1) * 1024);
    }
    const char* Wc = WsB + (tau & 1) * 8192;
    bf16x8_t af = *(const bf16x8_t*)(Abuf + (ar << rsh) + ((((ks << 2) | kslot) ^ akey) << 4));
    bf16x8_t bv[4];
#pragma unroll
    for (int i = 0; i < 4; ++i) bv[i] = *(const bf16x8_t*)(Wc + boff[i]);
#pragma unroll
    for (int ni = 0; ni < 4; ++ni)
      acc[ni] = __builtin_amdgcn_mfma_f32_16x16x32_bf16(af, bv[ni], acc[ni], 0, 0, 0);
    ++tau;
  };

  // ---- phase AB: wcat panel 0 -> a|bt in LDS ----
  for (int ks = 0; ks < 8; ++ks) kstep(Ys, 9, ks);
#pragma unroll
  for (int ni = 0; ni < 4; ++ni) {
    const int col = wc + ni * 16 + cbase;
#pragma unroll
    for (int j = 0; j < 4; ++j) {
      const int row = wr + rbase + j;
      const float v = acc[ni][j];
      ab[row * 136 + col] = f2bf(col < 64 ? tanhf(v) : v);
    }
    acc[ni] = zero;
  }
  __syncthreads();
  // ---- scan (2 batches x 64 dims on 128 threads) ----
  if (t < 128) {
    const int b = t >> 6, d = t & 63;
    float h = 0.f;
#pragma unroll
    for (int s = 0; s < 16; ++s) {
      const int row = b * 16 + s;
      const float a = bf2f(ab[row * 136 + d]);
      const float bt = bf2f(ab[row * 136 + 64 + d]);
      h = fmaf(a, h, bt);
      *(ushort*)(HsB + row * 128 + (((d >> 3) ^ (row & 7)) << 4) + (d & 7) * 2) = f2bf(h);
    }
  }

  f32x4_t gsv[2][4], dsv[2][4], xnv[2][4];
  // ---- phase G: wcat panels 1,2 -> sigmoid gate (f32 regs) ----
#pragma unroll
  for (int pp = 0; pp < 2; ++pp) {
    for (int ks = 0; ks < 8; ++ks) kstep(Ys, 9, ks);
#pragma unroll
    for (int ni = 0; ni < 4; ++ni) {
      const int col = pp * 128 + wc + ni * 16 + cbase;
#pragma unroll
      for (int j = 0; j < 4; ++j) {
        const float s = acc[ni][j] + gb[col];
        gsv[pp][ni][j] = 1.f / (1.f + expf(-s));
      }
      acc[ni] = zero;
    }
  }
  // ---- phase D: wcat panels 3,4 -> dt (f32 regs) ----
#pragma unroll
  for (int pp = 0; pp < 2; ++pp) {
    for (int ks = 0; ks < 8; ++ks) kstep(Ys, 9, ks);
#pragma unroll
    for (int ni = 0; ni < 4; ++ni) {
      const int col = pp * 128 + wc + ni * 16 + cbase;
#pragma unroll
      for (int j = 0; j < 4; ++j) dsv[pp][ni][j] = acc[ni][j] + db[col];
      acc[ni] = zero;
    }
  }
  // ---- phase YS: ys = hs @ Cw^T, then combine with packed xP ----
  const long rq16 = (m0 >> 4) + (wr >> 4);
#pragma unroll
  for (int pp = 0; pp < 2; ++pp) {
    for (int ks = 0; ks < 2; ++ks) kstep((const char*)HsB, 7, ks);
#pragma unroll
    for (int ni = 0; ni < 4; ++ni) {
      const int colq = pp * 8 + (wid & 1) * 4 + ni;
      const ushort4 x4 = *(const ushort4*)(xP + (rq16 * 16 + colq) * 256 + lane * 4);
#pragma unroll
      for (int j = 0; j < 4; ++j) {
        const float g = gsv[pp][ni][j], dv = dsv[pp][ni][j];
        const float xo = bf2f(j == 0 ? x4.x : (j == 1 ? x4.y : (j == 2 ? x4.z : x4.w)));
        xnv[pp][ni][j] = xo + acc[ni][j] * g + dv * (1.f - g);
      }
      acc[ni] = zero;
    }
  }
  // ---- LN stats (cross-wave via tiny LDS) ----
#pragma unroll
  for (int j = 0; j < 4; ++j) {
    float ps = 0.f, pq = 0.f;
#pragma unroll
    for (int pp = 0; pp < 2; ++pp)
#pragma unroll
      for (int ni = 0; ni < 4; ++ni) { const float v = xnv[pp][ni][j]; ps += v; pq += v * v; }
#pragma unroll
    for (int off = 1; off < 16; off <<= 1) {
      ps += __shfl_xor(ps, off, 64);
      pq += __shfl_xor(pq, off, 64);
    }
    if ((lane & 15) == 0) {
      const int row = wr + rbase + j;
      lsum[row][wid & 1] = ps;
      lsq[row][wid & 1] = pq;
    }
  }
  __syncthreads();
  // write xP (packed ushort4)
#pragma unroll
  for (int pp = 0; pp < 2; ++pp) {
#pragma unroll
    for (int ni = 0; ni < 4; ++ni) {
      const int colq = pp * 8 + (wid & 1) * 4 + ni;
      ushort4 o4;
      o4.x = f2bf(xnv[pp][ni][0]);
      o4.y = f2bf(xnv[pp][ni][1]);
      o4.z = f2bf(xnv[pp][ni][2]);
      o4.w = f2bf(xnv[pp][ni][3]);
      *(ushort4*)(xP + (rq16 * 16 + colq) * 256 + lane * 4) = o4;
    }
  }
  // LN -> y staged in LDS (linear rows), then coalesced copy out
#pragma unroll
  for (int j = 0; j < 4; ++j) {
    const int row = wr + rbase + j;
    const float sm = lsum[row][0] + lsum[row][1];
    const float q = lsq[row][0] + lsq[row][1];
    const float mean = sm * (1.f / 256.f);
    const float rstd = rsqrtf(q * (1.f / 256.f) - mean * mean + 1e-5f);
#pragma unroll
    for (int pp = 0; pp < 2; ++pp)
#pragma unroll
      for (int ni = 0; ni < 4; ++ni) {
        const int col = pp * 128 + wc + ni * 16 + cbase;
        *(ushort*)(Ys + row * 512 + col * 2) =
            f2bf((xnv[pp][ni][j] - mean) * rstd * lng[col] + lnb[col]);
      }
  }
  __syncthreads();
#pragma unroll
  for (int rr = 0; rr < 4; ++rr) {
    const int byte = rr * 4096 + t * 16;
    const int row = byte >> 9, off = byte & 511;
    const bf16x8_t v = *(const bf16x8_t*)(Ys + byte);
    *(bf16x8_t*)((char*)y + (m0 + row) * 512 + off) = v;
  }
}

// ========== ffn1: A-stationary GEMM, k-sliced W. K=256, gelu. (unchanged control) ==========
template <int NP, int MODE>
__global__ __launch_bounds__(256, 2)
void gemm_ws(const ushort* __restrict__ A, const ushort* __restrict__ Wks,
             const float* __restrict__ b1, const float* __restrict__ b2,
             ushort* __restrict__ outp, ushort* __restrict__ zab,
             ushort* __restrict__ zp) {
  constexpr int KS = 8;
  constexpr int N = NP * 128;
  constexpr int T = NP * KS;
  __shared__ __align__(16) char AsB[128 * 512];
  __shared__ __align__(16) char WsB[2 * 8192];

  const int t = threadIdx.x, lane = t & 63, wid = t >> 6;
  const long m0 = (long)blockIdx.x * 128;
  const int wr = (wid >> 1) * 64, wc = (wid & 1) * 64;
  const char* Ab = (const char*)A;
  const char* Wb = (const char*)Wks;

  {
    const int arow = lane >> 5;
    const int aps  = lane & 31;
#pragma unroll
    for (int j = 0; j < 16; ++j) {
      const int r = j * 8 + wid * 2 + arow;
      gload_lds16(Ab + (m0 + r) * 512 + (long)((aps ^ (r & 7)) << 4),
                  AsB + (j * 8 + wid * 2) * 512);
    }
  }
  {
    const int co = wid * 2;
    gload_lds16(Wb + co * 1024 + lane * 16, WsB + co * 1024);
    gload_lds16(Wb + (co + 1) * 1024 + lane * 16, WsB + (co + 1) * 1024);
  }

  const int krow = lane & 15, kslot = lane >> 4;
  int abase[4], akey[4], boff[4];
#pragma unroll
  for (int i = 0; i < 4; ++i) {
    const int ar = wr + i * 16 + krow;
    abase[i] = ar * 512;
    akey[i] = ar & 7;
    const int br = wc + i * 16 + krow;
    boff[i] = br * 64 + ((kslot ^ ((br >> 1) & 3)) << 4);
  }

  const f32x4_t zero = {0.f, 0.f, 0.f, 0.f};
  f32x4_t acc[4][4];
#pragma unroll
  for (int i = 0; i < 4; ++i)
#pragma unroll
    for (int j = 0; j < 4; ++j) acc[i][j] = zero;

  const int rbase = (lane >> 4) * 4, cbase = lane & 15;

  for (int tau = 0; tau < T; ++tau) {
    __syncthreads();
    if (tau + 1 < T) {
      const int co = wid * 2;
      char* dst = WsB + ((tau + 1) & 1) * 8192;
      const char* src = Wb + (long)(tau + 1) * 8192;
      gload_lds16(src + co * 1024 + lane * 16, dst + co * 1024);
      gload_lds16(src + (co + 1) * 1024 + lane * 16, dst + (co + 1) * 1024);
    }
    const int ks = tau & 7;
    const char* Wc = WsB + (tau & 1) * 8192;
    bf16x8_t af[4], bv[4];
#pragma unroll
    for (int i = 0; i < 4; ++i)
      af[i] = *(const bf16x8_t*)(AsB + abase[i] + ((((ks << 2) | kslot) ^ akey[i]) << 4));
#pragma unroll
    for (int i = 0; i < 4; ++i) bv[i] = *(const bf16x8_t*)(Wc + boff[i]);
#pragma unroll
    for (int mi = 0; mi < 4; ++mi)
#pragma unroll
      for (int ni = 0; ni < 4; ++ni)
        acc[mi][ni] = __builtin_amdgcn_mfma_f32_16x16x32_bf16(af[mi], bv[ni], acc[mi][ni], 0, 0, 0);

    if (ks == KS - 1) {
      const int np = tau >> 3;
#pragma unroll
      for (int mi = 0; mi < 4; ++mi) {
#pragma unroll
        for (int ni = 0; ni < 4; ++ni) {
          const int col = np * 128 + wc + ni * 16 + cbase;
#pragma unroll
          for (int j = 0; j < 4; ++j) {
            const long row = m0 + wr + mi * 16 + rbase + j;
            float s = acc[mi][ni][j] + b1[col];
            float o = 0.5f * s * (1.f + erff(s * 0.70710678118654752f));
            outp[row * N + col] = f2bf(o);
          }
          acc[mi][ni] = zero;
        }
      }
    }
  }
  (void)zab; (void)zp; (void)b2;
}

// ========== G3: N=256 GEMM + fused residual + LayerNorm; x packed, y row-major ==========
template <int K, int MODE>
__global__ __launch_bounds__(512)
void gemm_ln(const ushort* __restrict__ A, const ushort* __restrict__ W,
             const float* __restrict__ b1, ushort* __restrict__ xP,
             const float* __restrict__ lng, const float* __restrict__ lnb,
             ushort* __restrict__ y, int writex) {
  constexpr int KS = K / 32;
  __shared__ __align__(16) char WsB[2 * 16384];
  __shared__ __align__(16) char AsB[2 * 8192];
  __shared__ float lsum4[128][4], lsq4[128][4];

  const int t = threadIdx.x, lane = t & 63, wid = t >> 6;
  const int wr = (wid >> 2) * 64, wc = (wid & 3) * 64;
  const int lr = lane >> 2, lc = lane & 3;
  const int ra = wid * 16 + lr;
  const int saA = (lc ^ swzkey(ra)) << 4;
  const int rw0 = wid * 32 + lr, rw1 = rw0 + 16;
  const int sw0 = (lc ^ swzkey(rw0)) << 4;
  const int sw1 = (lc ^ swzkey(rw1)) << 4;
  const char* Ab = (const char*)A;
  const char* Wb = (const char*)W;
  constexpr long K2 = (long)K * 2;
  const long m0 = (long)blockIdx.x * 128;

  gload_lds16(Wb + (long)rw0 * K2 + sw0, WsB + wid * 2048);
  gload_lds16(Wb + (long)rw1 * K2 + sw1, WsB + wid * 2048 + 1024);
  gload_lds16(Ab + (m0 + ra) * K2 + saA, AsB + wid * 1024);

  const int krow = lane & 15, kslot = lane >> 4;
  int aoff[4], boff[4];
#pragma unroll
  for (int i = 0; i < 4; ++i) {
    int ar = wr + i * 16 + krow;
    aoff[i] = ar * 64 + ((kslot ^ swzkey(ar)) << 4);
    int br = wc + i * 16 + krow;
    boff[i] = br * 64 + ((kslot ^ swzkey(br)) << 4);
  }

  const f32x4_t zero = {0.f, 0.f, 0.f, 0.f};
  f32x4_t acc[4][4];
#pragma unroll
  for (int i = 0; i < 4; ++i)
#pragma unroll
    for (int j = 0; j < 4; ++j) acc[i][j] = zero;

  for (int tau = 0; tau < KS; ++tau) {
    __syncthreads();
    if (tau + 1 < KS) {
      const long kb = (long)(tau + 1) * 64;
      gload_lds16(Ab + (m0 + ra) * K2 + kb + saA, AsB + ((tau + 1) & 1) * 8192 + wid * 1024);
      char* wd = WsB + ((tau + 1) & 1) * 16384 + wid * 2048;
      gload_lds16(Wb + (long)rw0 * K2 + kb + sw0, wd);
      gload_lds16(Wb + (long)rw1 * K2 + kb + sw1, wd + 1024);
    }
    const char* Ac = AsB + (tau & 1) * 8192;
    const char* Wc = WsB + (tau & 1) * 16384;
    bf16x8_t af[4], bv[4];
#pragma unroll
    for (int i = 0; i < 4; ++i) af[i] = *(const bf16x8_t*)(Ac + aoff[i]);
#pragma unroll
    for (int i = 0; i < 4; ++i) bv[i] = *(const bf16x8_t*)(Wc + boff[i]);
#pragma unroll
    for (int mi = 0; mi < 4; ++mi)
#pragma unroll
      for (int ni = 0; ni < 4; ++ni)
        acc[mi][ni] = __builtin_amdgcn_mfma_f32_16x16x32_bf16(af[mi], bv[ni], acc[mi][ni], 0, 0, 0);
  }

  const int rbase = (lane >> 4) * 4;
  const int cbase = lane & 15;
  const long xbB = (long)blockIdx.x * 32768;
#pragma unroll
  for (int mi = 0; mi < 4; ++mi) {
    const int rq = (wid >> 2) * 4 + mi;
#pragma unroll
    for (int ni = 0; ni < 4; ++ni) {
      const int col = wc + ni * 16 + cbase;
      const int cq = (wid & 3) * 4 + ni;
      ushort4 x4;
      if constexpr (MODE == 3) x4 = *(const ushort4*)(xP + xbB + ((rq * 16 + cq) * 64 + lane) * 4);
#pragma unroll
      for (int j = 0; j < 4; ++j) {
        float v = acc[mi][ni][j] + b1[col];
        if constexpr (MODE == 3)
          v += bf2f(j == 0 ? x4.x : (j == 1 ? x4.y : (j == 2 ? x4.z : x4.w)));
        acc[mi][ni][j] = v;
      }
    }
  }
#pragma unroll
  for (int mi = 0; mi < 4; ++mi) {
#pragma unroll
    for (int j = 0; j < 4; ++j) {
      float ps = 0.f, pq = 0.f;
#pragma unroll
      for (int ni = 0; ni < 4; ++ni) { float v = acc[mi][ni][j]; ps += v; pq += v * v; }
#pragma unroll
      for (int off = 1; off < 16; off <<= 1) {
        ps += __shfl_xor(ps, off, 64);
        pq += __shfl_xor(pq, off, 64);
      }
      if ((lane & 15) == 0) {
        int r = wr + mi * 16 + (lane >> 4) * 4 + j;
        lsum4[r][wid & 3] = ps;
        lsq4[r][wid & 3] = pq;
      }
    }
  }
  __syncthreads();
#pragma unroll
  for (int mi = 0; mi < 4; ++mi) {
    const int rq = (wid >> 2) * 4 + mi;
#pragma unroll
    for (int ni = 0; ni < 4; ++ni) {
      const int cq = (wid & 3) * 4 + ni;
      if (writex) {
        ushort4 o4;
        o4.x = f2bf(acc[mi][ni][0]);
        o4.y = f2bf(acc[mi][ni][1]);
        o4.z = f2bf(acc[mi][ni][2]);
        o4.w = f2bf(acc[mi][ni][3]);
        *(ushort4*)(xP + xbB + ((rq * 16 + cq) * 64 + lane) * 4) = o4;
      }
    }
  }
#pragma unroll
  for (int mi = 0; mi < 4; ++mi) {
#pragma unroll
    for (int j = 0; j < 4; ++j) {
      const int r = wr + mi * 16 + rbase + j;
      const float s = lsum4[r][0] + lsum4[r][1] + lsum4[r][2] + lsum4[r][3];
      const float q = lsq4[r][0] + lsq4[r][1] + lsq4[r][2] + lsq4[r][3];
      const float mean = s * (1.f / 256.f);
      const float rstd = rsqrtf(q * (1.f / 256.f) - mean * mean + 1e-5f);
      const long row = m0 + r;
#pragma unroll
      for (int ni = 0; ni < 4; ++ni) {
        const int col = wc + ni * 16 + cbase;
        y[row * 256 + col] = f2bf((acc[mi][ni][j] - mean) * rstd * lng[col] + lnb[col]);
      }
    }
  }
}

// ---------------- head ----------------
__global__ __launch_bounds__(256)
void head_kernel(const ushort* __restrict__ yin, const float* __restrict__ attw,
                 const float* __restrict__ ow, const float* __restrict__ ob,
                 const float* __restrict__ cw, const float* __restrict__ cb,
                 float* __restrict__ out) {
  __shared__ float xf[16][256];
  __shared__ float lg[16], aw[16];
  __shared__ float vs[256], o1[128], lgc[40], lse[1];
  const int t = threadIdx.x, lane = t & 63, wid = t >> 6;
  const ushort* yb = yin + (long)blockIdx.x * 16 * 256;

  for (int r = wid; r < 16; r += 4) {
    ushort4 u = *(const ushort4*)(yb + r * 256 + lane * 4);
    int c = lane * 4;
    xf[r][c + 0] = bf2f(u.x);
    xf[r][c + 1] = bf2f(u.y);
    xf[r][c + 2] = bf2f(u.z);
    xf[r][c + 3] = bf2f(u.w);
  }
  __syncthreads();

  for (int r = wid; r < 16; r += 4) {
    const float* wv = attw + (r == 0 ? 0 : 256);
    int c = lane * 4;
    float s = xf[r][c] * wv[c] + xf[r][c + 1] * wv[c + 1] +
              xf[r][c + 2] * wv[c + 2] + xf[r][c + 3] * wv[c + 3];
#pragma unroll
    for (int off = 32; off > 0; off >>= 1) s += __shfl_xor(s, off, 64);
    if (lane == 0) lg[r] = s;
  }
  __syncthreads();

  if (t == 0) {
    float mx = -1e30f;
    for (int s2 = 1; s2 < 16; ++s2) mx = fmaxf(mx, lg[s2]);
    float den = 0.f;
    for (int s2 = 1; s2 < 16; ++s2) { float e = expf(lg[s2] - mx); aw[s2] = e; den += e; }
    float inv = 1.f / den;
    for (int s2 = 1; s2 < 16; ++s2) aw[s2] *= inv;
  }
  __syncthreads();

  float vh = xf[0][t];
  for (int s2 = 1; s2 < 16; ++s2) vh += aw[s2] * xf[s2][t];
  vs[t] = vh;
  __syncthreads();

  if (t < 128) {
    float s = ob[t];
    const float* w = ow + t * 256;
    for (int h2 = 0; h2 < 256; ++h2) s += w[h2] * vs[h2];
    o1[t] = fmaxf(s, 0.f);
  }
  __syncthreads();

  if (t < 40) {
    float s = cb[t];
    const float* w = cw + t * 128;
    for (int j = 0; j < 128; ++j) s += w[j] * o1[j];
    lgc[t] = s;
  }
  __syncthreads();

  if (t == 0) {
    float mx = -1e30f;
    for (int c2 = 0; c2 < 40; ++c2) mx = fmaxf(mx, lgc[c2]);
    float den = 0.f;
    for (int c2 = 0; c2 < 40; ++c2) den += expf(lgc[c2] - mx);
    lse[0] = mx + logf(den);
  }
  __syncthreads();
  if (t < 40) out[(long)blockIdx.x * 40 + t] = lgc[t] - lse[0];
}

// ---------------- host ----------------
extern "C" void kernel_launch(void* const* d_in, const int* in_sizes, int n_in,
                              void* d_out, int out_size, void* d_ws, size_t ws_size,
                              hipStream_t stream) {
  const float* data   = (const float*)d_in[0];
  const float* in_w   = (const float*)d_in[1];
  const float* in_b   = (const float*)d_in[2];
  const float* norm_g = (const float*)d_in[3];
  const float* norm_b = (const float*)d_in[4];
  const float* A_w    = (const float*)d_in[5];
  const float* B_w    = (const float*)d_in[6];
  const float* C_w    = (const float*)d_in[7];
  const float* D_w    = (const float*)d_in[8];
  const float* D_b    = (const float*)d_in[9];
  const float* gate_w = (const float*)d_in[10];
  const float* gate_b = (const float*)d_in[11];
  const float* ffn_w1 = (const float*)d_in[12];
  const float* ffn_b1 = (const float*)d_in[13];
  const float* ffn_w2 = (const float*)d_in[14];
  const float* ffn_b2 = (const float*)d_in[15];
  const float* fln_g  = (const float*)d_in[16];
  const float* fln_b  = (const float*)d_in[17];
  const float* out_w  = (const float*)d_in[18];
  const float* out_b  = (const float*)d_in[19];
  const float* cls_w  = (const float*)d_in[20];
  const float* cls_b  = (const float*)d_in[21];
  const float* attn_w = (const float*)d_in[22];
  const float* attn_b = (const float*)d_in[23];
  (void)in_sizes; (void)n_in; (void)out_size; (void)ws_size; (void)attn_b;

  char* ws = (char*)d_ws;
  ushort* xP    = (ushort*)(ws + 0);           // packed x
  ushort* y     = (ushort*)(ws + 67108864);    // row-major y
  ushort* tzp   = (ushort*)(ws + 134217728);   // t / datab (time-shared)
  ushort* wcat  = (ushort*)(ws + 318767104);
  ushort* inwb  = (ushort*)(ws + 320733184);
  ushort* w1b   = (ushort*)(ws + 320995328);
  ushort* w2b   = (ushort*)(ws + 322568192);
  ushort* cwb   = (ushort*)(ws + 324141056);
  ushort* wcatk = (ushort*)(ws + 324337664);   // 6*640*256*2 (k-sliced)
  ushort* w1k   = (ushort*)(ws + 326303744);   // 6*512*256*2 (k-sliced)
  ushort* cwk   = (ushort*)(ws + 327876608);   // 6*256*64*2  (k-sliced)
  ushort* datab = tzp;

  cvt_kernel<<<512, 256, 0, stream>>>(in_w, inwb, 131072);
  cvt_kernel<<<3072, 256, 0, stream>>>(ffn_w1, w1b, 786432);
  cvt_kernel<<<3072, 256, 0, stream>>>(ffn_w2, w2b, 786432);
  cvt_kernel<<<384, 256, 0, stream>>>(C_w, cwb, 98304);
  build_wcat<<<3840, 256, 0, stream>>>(A_w, B_w, gate_w, D_w, wcat);
  repack_gen<<<3840, 256, 0, stream>>>(wcat, wcatk, 256, 640 * 256, 6L * 640 * 256);
  repack_gen<<<3072, 256, 0, stream>>>(w1b, w1k, 256, 512 * 256, 6L * 512 * 256);
  repack_gen<<<384, 256, 0, stream>>>(cwb, cwk, 64, 256 * 64, 6L * 256 * 64);
  cvt4_kernel<<<65536, 256, 0, stream>>>(data, datab, 16777216);

  // input proj + fused LN(layer0): xP (packed), y
  gemm_ln<512, 0><<<dim3(1024), 512, 0, stream>>>(
      datab, inwb, in_b, xP, norm_g, norm_b, y, 1);

  for (int l = 0; l < 6; ++l) {
    mamba_fused<<<4096, 256, 0, stream>>>(
        y, xP, wcatk + (size_t)l * 640 * 256, cwk + (size_t)l * 16384,
        gate_b + l * 256, D_b + l * 256, norm_g + l * 256, norm_b + l * 256);
    gemm_ws<4, 2><<<1024, 256, 0, stream>>>(
        y, w1k + (size_t)l * 512 * 256, ffn_b1 + l * 512, nullptr, tzp, nullptr, nullptr);
    const float* lg2 = (l < 5) ? (norm_g + (l + 1) * 256) : fln_g;
    const float* lb2 = (l < 5) ? (norm_b + (l + 1) * 256) : fln_b;
    gemm_ln<512, 3><<<dim3(1024), 512, 0, stream>>>(
        tzp, w2b + (size_t)l * 256 * 512, ffn_b2 + l * 256, xP, lg2, lb2, y, (l < 5) ? 1 : 0);
  }

  head_kernel<<<8192, 256, 0, stream>>>(y, attn_w, out_w, out_b, cls_w, cls_b, (float*)d_out);
}